// Round 1
// baseline (535.490 us; speedup 1.0000x reference)
//
#include <hip/hip_runtime.h>
#include <hip/hip_bf16.h>

typedef __attribute__((ext_vector_type(8))) __bf16 bf16x8;
typedef __attribute__((ext_vector_type(4))) float f32x4;

#define E_ 768
#define HEADS 12
#define HD 64
#define S_ 2048
#define B_ 4

__device__ inline unsigned short f2bf(float f) {
    union { float f; unsigned int u; } x{f};
    unsigned int r = x.u + 0x7FFFu + ((x.u >> 16) & 1u);
    return (unsigned short)(r >> 16);
}

// ---------- fp32 -> bf16 elementwise (x) ----------
__global__ void cvt_kernel(const float* __restrict__ in, unsigned short* __restrict__ out, int n4) {
    int i = blockIdx.x * blockDim.x + threadIdx.x;
    if (i < n4) {
        float4 v = reinterpret_cast<const float4*>(in)[i];
        ushort4 o;
        o.x = f2bf(v.x); o.y = f2bf(v.y); o.z = f2bf(v.z); o.w = f2bf(v.w);
        reinterpret_cast<ushort4*>(out)[i] = o;
    }
}

// ---------- transpose + convert: w[K][N] fp32 -> wT[N][K] bf16 ----------
__global__ void transpose_cvt(const float* __restrict__ w, unsigned short* __restrict__ wT,
                              int K, int N) {
    __shared__ float tile[32][33];
    int n0 = blockIdx.x * 32, k0 = blockIdx.y * 32;
    int tx = threadIdx.x, ty = threadIdx.y;
    tile[ty][tx] = w[(size_t)(k0 + ty) * N + n0 + tx];
    __syncthreads();
    wT[(size_t)(n0 + ty) * K + k0 + tx] = f2bf(tile[tx][ty]);
}

// ---------- bf16 MFMA GEMM: A[M][K] x Bt[N][K]^T, 128x128 block tile ----------
// MODE 0: qkv scatter epilogue (writes Q,K [BH][S][D] and V transposed [BH][D][S], bf16)
// MODE 1: fp32 output with bias
template<int MODE>
__global__ __launch_bounds__(256) void gemm16(
    const unsigned short* __restrict__ A, const unsigned short* __restrict__ Bt,
    const float* __restrict__ bias,
    unsigned short* __restrict__ Qo, unsigned short* __restrict__ Ko,
    unsigned short* __restrict__ Vt, float* __restrict__ Of,
    int M, int N, int K)
{
    int w = threadIdx.x >> 6, lane = threadIdx.x & 63;
    int lr = lane & 15, lc = lane >> 4;
    int row0 = blockIdx.y * 128 + (w >> 1) * 64;
    int col0 = blockIdx.x * 128 + (w & 1) * 64;

    f32x4 acc[4][4] = {};
    const unsigned short* Ap = A + (size_t)row0 * K + lc * 8;
    const unsigned short* Bp = Bt + (size_t)col0 * K + lc * 8;

    for (int k = 0; k < K; k += 32) {
        bf16x8 a[4], b[4];
#pragma unroll
        for (int i = 0; i < 4; i++)
            a[i] = *reinterpret_cast<const bf16x8*>(Ap + (size_t)(i * 16 + lr) * K + k);
#pragma unroll
        for (int j = 0; j < 4; j++)
            b[j] = *reinterpret_cast<const bf16x8*>(Bp + (size_t)(j * 16 + lr) * K + k);
#pragma unroll
        for (int i = 0; i < 4; i++)
#pragma unroll
            for (int j = 0; j < 4; j++)
                acc[i][j] = __builtin_amdgcn_mfma_f32_16x16x32_bf16(a[i], b[j], acc[i][j], 0, 0, 0);
    }

#pragma unroll
    for (int i = 0; i < 4; i++)
#pragma unroll
        for (int j = 0; j < 4; j++) {
            int col = col0 + j * 16 + lr;
            float bv = bias[col];
#pragma unroll
            for (int r = 0; r < 4; r++) {
                int row = row0 + i * 16 + lc * 4 + r;
                float val = acc[i][j][r] + bv;
                if constexpr (MODE == 0) {
                    int bb = row >> 11, s = row & (S_ - 1);
                    int which = col / E_;
                    int nn = col - which * E_;
                    int h = nn >> 6, d = nn & 63;
                    size_t bh = (size_t)(bb * HEADS + h);
                    if (which == 0)      Qo[(bh * S_ + s) * HD + d] = f2bf(val);
                    else if (which == 1) Ko[(bh * S_ + s) * HD + d] = f2bf(val);
                    else                 Vt[(bh * HD + d) * S_ + s] = f2bf(val);
                } else {
                    Of[(size_t)row * N + col] = val;
                }
            }
        }
}

// ---------- causal flash attention ----------
// grid (S/64, B*H), block 256 (4 independent waves, 16 q-rows each)
__global__ __launch_bounds__(256) void attn_kernel(
    const unsigned short* __restrict__ Q, const unsigned short* __restrict__ Kd,
    const unsigned short* __restrict__ Vt, unsigned short* __restrict__ O)
{
    __shared__ unsigned short Pl[4][16][40];   // per-wave P tile, padded (stride 40)
    int w = threadIdx.x >> 6, lane = threadIdx.x & 63;
    int lr = lane & 15, lc = lane >> 4;
    int bh = blockIdx.y;
    int q0 = blockIdx.x * 64 + w * 16;

    const unsigned short* Qb = Q + (size_t)bh * S_ * HD;
    const unsigned short* Kb = Kd + (size_t)bh * S_ * HD;
    const unsigned short* Vb = Vt + (size_t)bh * HD * S_;

    bf16x8 aq[2];
#pragma unroll
    for (int dc = 0; dc < 2; dc++)
        aq[dc] = *reinterpret_cast<const bf16x8*>(Qb + (size_t)(q0 + lr) * HD + dc * 32 + lc * 8);

    f32x4 accO[4] = {};
    float m[4], l[4];
#pragma unroll
    for (int r = 0; r < 4; r++) { m[r] = -INFINITY; l[r] = 0.f; }

    int kv_end = q0 + 16;
    for (int kv0 = 0; kv0 < kv_end; kv0 += 32) {
        f32x4 accS[2] = {};
#pragma unroll
        for (int kt = 0; kt < 2; kt++)
#pragma unroll
            for (int dc = 0; dc < 2; dc++) {
                bf16x8 bk = *reinterpret_cast<const bf16x8*>(
                    Kb + (size_t)(kv0 + kt * 16 + lr) * HD + dc * 32 + lc * 8);
                accS[kt] = __builtin_amdgcn_mfma_f32_16x16x32_bf16(aq[dc], bk, accS[kt], 0, 0, 0);
            }

        // scale + causal mask + row stats
        float p[2][4], rowmax[4], rowsum[4];
#pragma unroll
        for (int r = 0; r < 4; r++) rowmax[r] = -1e30f;
#pragma unroll
        for (int kt = 0; kt < 2; kt++) {
            int kvcol = kv0 + kt * 16 + lr;
#pragma unroll
            for (int r = 0; r < 4; r++) {
                int qrow = q0 + lc * 4 + r;
                float s = accS[kt][r] * 0.125f;
                if (kvcol > qrow) s = -1e30f;
                p[kt][r] = s;
                rowmax[r] = fmaxf(rowmax[r], s);
            }
        }
#pragma unroll
        for (int off = 1; off < 16; off <<= 1)
#pragma unroll
            for (int r = 0; r < 4; r++)
                rowmax[r] = fmaxf(rowmax[r], __shfl_xor(rowmax[r], off));

#pragma unroll
        for (int r = 0; r < 4; r++) {
            float mn = fmaxf(m[r], rowmax[r]);
            float sc = __expf(m[r] - mn);
            float rs = 0.f;
#pragma unroll
            for (int kt = 0; kt < 2; kt++) {
                float e = __expf(p[kt][r] - mn);
                p[kt][r] = e;
                rs += e;
            }
            rowsum[r] = rs;
            m[r] = mn;
            l[r] = l[r] * sc;
#pragma unroll
            for (int dt = 0; dt < 4; dt++) accO[dt][r] *= sc;
        }
#pragma unroll
        for (int off = 1; off < 16; off <<= 1)
#pragma unroll
            for (int r = 0; r < 4; r++)
                rowsum[r] += __shfl_xor(rowsum[r], off);
#pragma unroll
        for (int r = 0; r < 4; r++) l[r] += rowsum[r];

        // P -> LDS (bf16), transpose via layout
#pragma unroll
        for (int kt = 0; kt < 2; kt++)
#pragma unroll
            for (int r = 0; r < 4; r++)
                Pl[w][lc * 4 + r][kt * 16 + lr] = f2bf(p[kt][r]);
        asm volatile("s_waitcnt lgkmcnt(0)" ::: "memory");
        bf16x8 ap = *reinterpret_cast<const bf16x8*>(&Pl[w][lr][lc * 8]);

#pragma unroll
        for (int dt = 0; dt < 4; dt++) {
            bf16x8 bv = *reinterpret_cast<const bf16x8*>(
                Vb + (size_t)(dt * 16 + lr) * S_ + kv0 + lc * 8);
            accO[dt] = __builtin_amdgcn_mfma_f32_16x16x32_bf16(ap, bv, accO[dt], 0, 0, 0);
        }
    }

    int bb = bh / HEADS, h = bh - bb * HEADS;
#pragma unroll
    for (int dt = 0; dt < 4; dt++)
#pragma unroll
        for (int r = 0; r < 4; r++) {
            int qrow = q0 + lc * 4 + r;
            float v = accO[dt][r] / l[r];
            O[((size_t)(bb * S_ + qrow)) * E_ + h * HD + dt * 16 + lr] = f2bf(v);
        }
}

extern "C" void kernel_launch(void* const* d_in, const int* in_sizes, int n_in,
                              void* d_out, int out_size, void* d_ws, size_t ws_size,
                              hipStream_t stream) {
    const float* x      = (const float*)d_in[0];
    const float* w_attn = (const float*)d_in[1];
    const float* b_attn = (const float*)d_in[2];
    const float* w_proj = (const float*)d_in[3];
    const float* b_proj = (const float*)d_in[4];
    float* out = (float*)d_out;

    char* ws = (char*)d_ws;
    const size_t M = (size_t)B_ * S_;             // 8192
    unsigned short* xb  = (unsigned short*)(ws);                         // 8192*768
    unsigned short* waT = (unsigned short*)(ws + 12582912);              // 2304*768
    unsigned short* wpT = (unsigned short*)(ws + 16121856);              // 768*768
    unsigned short* Qb  = (unsigned short*)(ws + 17301504);              // BH*S*D
    unsigned short* Kb  = (unsigned short*)(ws + 29884416);
    unsigned short* Vt  = (unsigned short*)(ws + 42467328);
    unsigned short* AO  = (unsigned short*)(ws + 55050240);              // 8192*768

    int n4 = (int)(M * E_ / 4);
    cvt_kernel<<<(n4 + 255) / 256, 256, 0, stream>>>(x, xb, n4);
    transpose_cvt<<<dim3(3 * E_ / 32, E_ / 32), dim3(32, 32), 0, stream>>>(w_attn, waT, E_, 3 * E_);
    transpose_cvt<<<dim3(E_ / 32, E_ / 32), dim3(32, 32), 0, stream>>>(w_proj, wpT, E_, E_);

    gemm16<0><<<dim3(3 * E_ / 128, M / 128), 256, 0, stream>>>(
        xb, waT, b_attn, Qb, Kb, Vt, nullptr, (int)M, 3 * E_, E_);

    attn_kernel<<<dim3(S_ / 64, B_ * HEADS), 256, 0, stream>>>(Qb, Kb, Vt, AO);

    gemm16<1><<<dim3(E_ / 128, M / 128), 256, 0, stream>>>(
        AO, wpT, b_proj, nullptr, nullptr, nullptr, out, (int)M, E_, E_);
}

// Round 2
// 520.937 us; speedup vs baseline: 1.0279x; 1.0279x over previous
//
#include <hip/hip_runtime.h>
#include <hip/hip_bf16.h>

typedef __attribute__((ext_vector_type(8))) __bf16 bf16x8;
typedef __attribute__((ext_vector_type(4))) float f32x4;

#define E_ 768
#define HEADS 12
#define HD 64
#define S_ 2048
#define B_ 4

__device__ inline unsigned short f2bf(float f) {
    union { float f; unsigned int u; } x{f};
    unsigned int r = x.u + 0x7FFFu + ((x.u >> 16) & 1u);
    return (unsigned short)(r >> 16);
}

// ---------- fp32 -> bf16 elementwise (x) ----------
__global__ void cvt_kernel(const float* __restrict__ in, unsigned short* __restrict__ out, int n4) {
    int i = blockIdx.x * blockDim.x + threadIdx.x;
    if (i < n4) {
        float4 v = reinterpret_cast<const float4*>(in)[i];
        ushort4 o;
        o.x = f2bf(v.x); o.y = f2bf(v.y); o.z = f2bf(v.z); o.w = f2bf(v.w);
        reinterpret_cast<ushort4*>(out)[i] = o;
    }
}

// ---------- transpose + convert: w[K][N] fp32 -> wT[N][K] bf16 ----------
__global__ void transpose_cvt(const float* __restrict__ w, unsigned short* __restrict__ wT,
                              int K, int N) {
    __shared__ float tile[32][33];
    int n0 = blockIdx.x * 32, k0 = blockIdx.y * 32;
    int tx = threadIdx.x, ty = threadIdx.y;
    tile[ty][tx] = w[(size_t)(k0 + ty) * N + n0 + tx];
    __syncthreads();
    wT[(size_t)(n0 + ty) * K + k0 + tx] = f2bf(tile[tx][ty]);
}

// ---------- bf16 MFMA GEMM: A[M][K] x Bt[N][K]^T, 128x128 block tile ----------
template<int MODE>
__global__ __launch_bounds__(256) void gemm16(
    const unsigned short* __restrict__ A, const unsigned short* __restrict__ Bt,
    const float* __restrict__ bias,
    unsigned short* __restrict__ Qo, unsigned short* __restrict__ Ko,
    unsigned short* __restrict__ Vt, float* __restrict__ Of,
    int M, int N, int K)
{
    int w = threadIdx.x >> 6, lane = threadIdx.x & 63;
    int lr = lane & 15, lc = lane >> 4;
    int row0 = blockIdx.y * 128 + (w >> 1) * 64;
    int col0 = blockIdx.x * 128 + (w & 1) * 64;

    f32x4 acc[4][4] = {};
    const unsigned short* Ap = A + (size_t)row0 * K + lc * 8;
    const unsigned short* Bp = Bt + (size_t)col0 * K + lc * 8;

    for (int k = 0; k < K; k += 32) {
        bf16x8 a[4], b[4];
#pragma unroll
        for (int i = 0; i < 4; i++)
            a[i] = *reinterpret_cast<const bf16x8*>(Ap + (size_t)(i * 16 + lr) * K + k);
#pragma unroll
        for (int j = 0; j < 4; j++)
            b[j] = *reinterpret_cast<const bf16x8*>(Bp + (size_t)(j * 16 + lr) * K + k);
#pragma unroll
        for (int i = 0; i < 4; i++)
#pragma unroll
            for (int j = 0; j < 4; j++)
                acc[i][j] = __builtin_amdgcn_mfma_f32_16x16x32_bf16(a[i], b[j], acc[i][j], 0, 0, 0);
    }

#pragma unroll
    for (int i = 0; i < 4; i++)
#pragma unroll
        for (int j = 0; j < 4; j++) {
            int col = col0 + j * 16 + lr;
            float bv = bias[col];
#pragma unroll
            for (int r = 0; r < 4; r++) {
                int row = row0 + i * 16 + lc * 4 + r;
                float val = acc[i][j][r] + bv;
                if constexpr (MODE == 0) {
                    int bb = row >> 11, s = row & (S_ - 1);
                    int which = col / E_;
                    int nn = col - which * E_;
                    int h = nn >> 6, d = nn & 63;
                    size_t bh = (size_t)(bb * HEADS + h);
                    if (which == 0)      Qo[(bh * S_ + s) * HD + d] = f2bf(val);
                    else if (which == 1) Ko[(bh * S_ + s) * HD + d] = f2bf(val);
                    else                 Vt[(bh * HD + d) * S_ + s] = f2bf(val);
                } else {
                    Of[(size_t)row * N + col] = val;
                }
            }
        }
}

// ---------- causal flash attention, light+heavy paired q-tiles ----------
// grid (16, B*H), block 256. Wave p = blockIdx.x*4+w owns q-tiles p and 127-p
// (16 rows each). Iterates heavy tile's KV range with KVBLK=64; light tile
// piggybacks on the same K/V fragments while kv0 < light_end.
__global__ __launch_bounds__(256) void attn_kernel(
    const unsigned short* __restrict__ Q, const unsigned short* __restrict__ Kd,
    const unsigned short* __restrict__ Vt, unsigned short* __restrict__ O)
{
    __shared__ unsigned short Pl[4][2][16][72];   // [wave][tile H/L][q][kv] padded
    int w = threadIdx.x >> 6, lane = threadIdx.x & 63;
    int lr = lane & 15, lc = lane >> 4;
    int bh = blockIdx.y;
    int p = blockIdx.x * 4 + w;        // 0..63
    int qL = p * 16;
    int qH = (127 - p) * 16;
    int endL = qL + 16, endH = qH + 16;

    const unsigned short* Qb = Q + (size_t)bh * S_ * HD;
    const unsigned short* Kb = Kd + (size_t)bh * S_ * HD;
    const unsigned short* Vb = Vt + (size_t)bh * HD * S_;

    bf16x8 aqL[2], aqH[2];
#pragma unroll
    for (int dc = 0; dc < 2; dc++) {
        aqL[dc] = *reinterpret_cast<const bf16x8*>(Qb + (size_t)(qL + lr) * HD + dc * 32 + lc * 8);
        aqH[dc] = *reinterpret_cast<const bf16x8*>(Qb + (size_t)(qH + lr) * HD + dc * 32 + lc * 8);
    }

    f32x4 oL[4] = {}, oH[4] = {};
    float mL[4], lLs[4], mH[4], lHs[4];
#pragma unroll
    for (int r = 0; r < 4; r++) { mL[r] = mH[r] = -INFINITY; lLs[r] = lHs[r] = 0.f; }

    for (int kv0 = 0; kv0 < endH; kv0 += 64) {
        bool doL = kv0 < endL;
        float pH[4][4], pL[4][4], rmH[4], rmL[4];
#pragma unroll
        for (int r = 0; r < 4; r++) { rmH[r] = -1e30f; rmL[r] = -1e30f; }

#pragma unroll
        for (int kt = 0; kt < 4; kt++) {
            int krow = kv0 + kt * 16 + lr;
            bf16x8 bk0 = *reinterpret_cast<const bf16x8*>(Kb + (size_t)krow * HD + lc * 8);
            bf16x8 bk1 = *reinterpret_cast<const bf16x8*>(Kb + (size_t)krow * HD + 32 + lc * 8);
            f32x4 sH = {};
            sH = __builtin_amdgcn_mfma_f32_16x16x32_bf16(aqH[0], bk0, sH, 0, 0, 0);
            sH = __builtin_amdgcn_mfma_f32_16x16x32_bf16(aqH[1], bk1, sH, 0, 0, 0);
#pragma unroll
            for (int r = 0; r < 4; r++) {
                float s = sH[r] * 0.125f;
                if (krow - lr + lr > qH + lc * 4 + r) s = -1e30f;   // kvcol > qrow
                pH[kt][r] = s;
                rmH[r] = fmaxf(rmH[r], s);
            }
            if (doL) {
                f32x4 sL = {};
                sL = __builtin_amdgcn_mfma_f32_16x16x32_bf16(aqL[0], bk0, sL, 0, 0, 0);
                sL = __builtin_amdgcn_mfma_f32_16x16x32_bf16(aqL[1], bk1, sL, 0, 0, 0);
#pragma unroll
                for (int r = 0; r < 4; r++) {
                    float s = sL[r] * 0.125f;
                    if (krow > qL + lc * 4 + r) s = -1e30f;
                    pL[kt][r] = s;
                    rmL[r] = fmaxf(rmL[r], s);
                }
            }
        }

        // row-max reduce over the 16 kv lanes (lr), both tiles in flight
#pragma unroll
        for (int off = 1; off < 16; off <<= 1)
#pragma unroll
            for (int r = 0; r < 4; r++) {
                rmH[r] = fmaxf(rmH[r], __shfl_xor(rmH[r], off));
                if (doL) rmL[r] = fmaxf(rmL[r], __shfl_xor(rmL[r], off));
            }

        float rsH[4], rsL[4];
#pragma unroll
        for (int r = 0; r < 4; r++) {
            float mn = fmaxf(mH[r], rmH[r]);
            float sc = __expf(mH[r] - mn);
            float rs = 0.f;
#pragma unroll
            for (int kt = 0; kt < 4; kt++) {
                float e = __expf(pH[kt][r] - mn);
                pH[kt][r] = e; rs += e;
            }
            rsH[r] = rs; mH[r] = mn; lHs[r] *= sc;
#pragma unroll
            for (int dt = 0; dt < 4; dt++) oH[dt][r] *= sc;
            if (doL) {
                float mnl = fmaxf(mL[r], rmL[r]);
                float scl = __expf(mL[r] - mnl);
                float rsl = 0.f;
#pragma unroll
                for (int kt = 0; kt < 4; kt++) {
                    float e = __expf(pL[kt][r] - mnl);
                    pL[kt][r] = e; rsl += e;
                }
                rsL[r] = rsl; mL[r] = mnl; lLs[r] *= scl;
#pragma unroll
                for (int dt = 0; dt < 4; dt++) oL[dt][r] *= scl;
            }
        }
#pragma unroll
        for (int off = 1; off < 16; off <<= 1)
#pragma unroll
            for (int r = 0; r < 4; r++) {
                rsH[r] += __shfl_xor(rsH[r], off);
                if (doL) rsL[r] += __shfl_xor(rsL[r], off);
            }
#pragma unroll
        for (int r = 0; r < 4; r++) {
            lHs[r] += rsH[r];
            if (doL) lLs[r] += rsL[r];
        }

        // P -> LDS (transpose to A-fragment layout)
#pragma unroll
        for (int kt = 0; kt < 4; kt++)
#pragma unroll
            for (int r = 0; r < 4; r++) {
                Pl[w][0][lc * 4 + r][kt * 16 + lr] = f2bf(pH[kt][r]);
                if (doL) Pl[w][1][lc * 4 + r][kt * 16 + lr] = f2bf(pL[kt][r]);
            }
        asm volatile("s_waitcnt lgkmcnt(0)" ::: "memory");

        bf16x8 apH[2], apL[2];
#pragma unroll
        for (int kc = 0; kc < 2; kc++) {
            apH[kc] = *reinterpret_cast<const bf16x8*>(&Pl[w][0][lr][kc * 32 + lc * 8]);
            if (doL) apL[kc] = *reinterpret_cast<const bf16x8*>(&Pl[w][1][lr][kc * 32 + lc * 8]);
        }

#pragma unroll
        for (int dt = 0; dt < 4; dt++) {
#pragma unroll
            for (int kc = 0; kc < 2; kc++) {
                bf16x8 bv = *reinterpret_cast<const bf16x8*>(
                    Vb + (size_t)(dt * 16 + lr) * S_ + kv0 + kc * 32 + lc * 8);
                oH[dt] = __builtin_amdgcn_mfma_f32_16x16x32_bf16(apH[kc], bv, oH[dt], 0, 0, 0);
                if (doL) oL[dt] = __builtin_amdgcn_mfma_f32_16x16x32_bf16(apL[kc], bv, oL[dt], 0, 0, 0);
            }
        }
    }

    int bb = bh / HEADS, h = bh - bb * HEADS;
#pragma unroll
    for (int dt = 0; dt < 4; dt++)
#pragma unroll
        for (int r = 0; r < 4; r++) {
            int col = h * HD + dt * 16 + lr;
            int qrH = qH + lc * 4 + r;
            O[((size_t)(bb * S_ + qrH)) * E_ + col] = f2bf(oH[dt][r] / lHs[r]);
            int qrL = qL + lc * 4 + r;
            O[((size_t)(bb * S_ + qrL)) * E_ + col] = f2bf(oL[dt][r] / lLs[r]);
        }
}

extern "C" void kernel_launch(void* const* d_in, const int* in_sizes, int n_in,
                              void* d_out, int out_size, void* d_ws, size_t ws_size,
                              hipStream_t stream) {
    const float* x      = (const float*)d_in[0];
    const float* w_attn = (const float*)d_in[1];
    const float* b_attn = (const float*)d_in[2];
    const float* w_proj = (const float*)d_in[3];
    const float* b_proj = (const float*)d_in[4];
    float* out = (float*)d_out;

    char* ws = (char*)d_ws;
    const size_t M = (size_t)B_ * S_;             // 8192
    unsigned short* xb  = (unsigned short*)(ws);                         // 8192*768
    unsigned short* waT = (unsigned short*)(ws + 12582912);              // 2304*768
    unsigned short* wpT = (unsigned short*)(ws + 16121856);              // 768*768
    unsigned short* Qb  = (unsigned short*)(ws + 17301504);              // BH*S*D
    unsigned short* Kb  = (unsigned short*)(ws + 29884416);
    unsigned short* Vt  = (unsigned short*)(ws + 42467328);
    unsigned short* AO  = (unsigned short*)(ws + 55050240);              // 8192*768

    int n4 = (int)(M * E_ / 4);
    cvt_kernel<<<(n4 + 255) / 256, 256, 0, stream>>>(x, xb, n4);
    transpose_cvt<<<dim3(3 * E_ / 32, E_ / 32), dim3(32, 32), 0, stream>>>(w_attn, waT, E_, 3 * E_);
    transpose_cvt<<<dim3(E_ / 32, E_ / 32), dim3(32, 32), 0, stream>>>(w_proj, wpT, E_, E_);

    gemm16<0><<<dim3(3 * E_ / 128, M / 128), 256, 0, stream>>>(
        xb, waT, b_attn, Qb, Kb, Vt, nullptr, (int)M, 3 * E_, E_);

    attn_kernel<<<dim3(16, B_ * HEADS), 256, 0, stream>>>(Qb, Kb, Vt, AO);

    gemm16<1><<<dim3(E_ / 128, M / 128), 256, 0, stream>>>(
        AO, wpT, b_proj, nullptr, nullptr, nullptr, out, (int)M, E_, E_);
}

// Round 6
// 384.897 us; speedup vs baseline: 1.3913x; 1.3534x over previous
//
#include <hip/hip_runtime.h>
#include <hip/hip_bf16.h>

typedef __attribute__((ext_vector_type(8))) __bf16 bf16x8;
typedef __attribute__((ext_vector_type(4))) float f32x4;

#define E_ 768
#define HEADS 12
#define HD 64
#define S_ 2048
#define B_ 4

__device__ inline unsigned short f2bf(float f) {
    union { float f; unsigned int u; } x{f};
    unsigned int r = x.u + 0x7FFFu + ((x.u >> 16) & 1u);
    return (unsigned short)(r >> 16);
}

// ---------- fp32 -> bf16 elementwise (x) ----------
__global__ void cvt_kernel(const float* __restrict__ in, unsigned short* __restrict__ out, int n4) {
    int i = blockIdx.x * blockDim.x + threadIdx.x;
    if (i < n4) {
        float4 v = reinterpret_cast<const float4*>(in)[i];
        ushort4 o;
        o.x = f2bf(v.x); o.y = f2bf(v.y); o.z = f2bf(v.z); o.w = f2bf(v.w);
        reinterpret_cast<ushort4*>(out)[i] = o;
    }
}

// ---------- transpose + convert: w[K][N] fp32 -> wT[N][K] bf16 ----------
__global__ void transpose_cvt(const float* __restrict__ w, unsigned short* __restrict__ wT,
                              int K, int N) {
    __shared__ float tile[32][33];
    int n0 = blockIdx.x * 32, k0 = blockIdx.y * 32;
    int tx = threadIdx.x, ty = threadIdx.y;
    tile[ty][tx] = w[(size_t)(k0 + ty) * N + n0 + tx];
    __syncthreads();
    wT[(size_t)(n0 + ty) * K + k0 + tx] = f2bf(tile[tx][ty]);
}

// ---------- bf16 MFMA GEMM: A[M][K] x Bt[N][K]^T, 128x128 block tile ----------
template<int MODE>
__global__ __launch_bounds__(256) void gemm16(
    const unsigned short* __restrict__ A, const unsigned short* __restrict__ Bt,
    const float* __restrict__ bias,
    unsigned short* __restrict__ Qo, unsigned short* __restrict__ Ko,
    unsigned short* __restrict__ Vt, float* __restrict__ Of,
    int M, int N, int K)
{
    int w = threadIdx.x >> 6, lane = threadIdx.x & 63;
    int lr = lane & 15, lc = lane >> 4;
    int row0 = blockIdx.y * 128 + (w >> 1) * 64;
    int col0 = blockIdx.x * 128 + (w & 1) * 64;

    f32x4 acc[4][4] = {};
    const unsigned short* Ap = A + (size_t)row0 * K + lc * 8;
    const unsigned short* Bp = Bt + (size_t)col0 * K + lc * 8;

    for (int k = 0; k < K; k += 32) {
        bf16x8 a[4], b[4];
#pragma unroll
        for (int i = 0; i < 4; i++)
            a[i] = *reinterpret_cast<const bf16x8*>(Ap + (size_t)(i * 16 + lr) * K + k);
#pragma unroll
        for (int j = 0; j < 4; j++)
            b[j] = *reinterpret_cast<const bf16x8*>(Bp + (size_t)(j * 16 + lr) * K + k);
#pragma unroll
        for (int i = 0; i < 4; i++)
#pragma unroll
            for (int j = 0; j < 4; j++)
                acc[i][j] = __builtin_amdgcn_mfma_f32_16x16x32_bf16(a[i], b[j], acc[i][j], 0, 0, 0);
    }

#pragma unroll
    for (int i = 0; i < 4; i++)
#pragma unroll
        for (int j = 0; j < 4; j++) {
            int col = col0 + j * 16 + lr;
            float bv = bias[col];
#pragma unroll
            for (int r = 0; r < 4; r++) {
                int row = row0 + i * 16 + lc * 4 + r;
                float val = acc[i][j][r] + bv;
                if constexpr (MODE == 0) {
                    int bb = row >> 11, s = row & (S_ - 1);
                    int which = col / E_;
                    int nn = col - which * E_;
                    int h = nn >> 6, d = nn & 63;
                    size_t bh = (size_t)(bb * HEADS + h);
                    if (which == 0)      Qo[(bh * S_ + s) * HD + d] = f2bf(val);
                    else if (which == 1) Ko[(bh * S_ + s) * HD + d] = f2bf(val);
                    else                 Vt[(bh * HD + d) * S_ + s] = f2bf(val);
                } else {
                    Of[(size_t)row * N + col] = val;
                }
            }
        }
}

// ---------- causal flash attention ----------
// grid (16, B*H), block 256 = 4 waves. Block bp owns 64-row q-tiles bp and
// 31-bp; wave w takes 16-row slices of both. K/V tiles (64x72 u16, padded)
// staged in LDS, double-buffered, shared by all 4 waves.
// BISECT R6: softmax internals reverted to R2's exact passing math
// (expf, *0.125, -1e30 mask, -INF init, per-iteration reduced l).
__global__ __launch_bounds__(256) void attn_kernel(
    const unsigned short* __restrict__ Q, const unsigned short* __restrict__ Kd,
    const unsigned short* __restrict__ Vt, unsigned short* __restrict__ O)
{
    __shared__ unsigned short Ksh[2][64 * 72];
    __shared__ unsigned short Vsh[2][64 * 72];
    __shared__ unsigned short Pl[4][2][16][72];

    const int t = threadIdx.x;
    const int w = t >> 6, lane = t & 63;
    const int lr = lane & 15, lc = lane >> 4;
    const int bh = blockIdx.y;
    const int bp = blockIdx.x;
    const int tTL = bp, tTH = 31 - bp;
    const int qL = tTL * 64 + w * 16, qH = tTH * 64 + w * 16;
    const int endL = qL + 16;
    const int endBlk = (tTH + 1) * 64;

    const unsigned short* Qb = Q + (size_t)bh * S_ * HD;
    const unsigned short* Kb = Kd + (size_t)bh * S_ * HD;
    const unsigned short* Vb = Vt + (size_t)bh * HD * S_;

    // staging: thread t covers rows srow, srow+32; ushort cols [scolu, scolu+8)
    const int srow = t >> 3;
    const int scolu = (t & 7) * 8;

    bf16x8 aqL[2], aqH[2];
#pragma unroll
    for (int dc = 0; dc < 2; dc++) {
        aqL[dc] = *reinterpret_cast<const bf16x8*>(Qb + (size_t)(qL + lr) * HD + dc * 32 + lc * 8);
        aqH[dc] = *reinterpret_cast<const bf16x8*>(Qb + (size_t)(qH + lr) * HD + dc * 32 + lc * 8);
    }

    f32x4 oL[4] = {}, oH[4] = {};
    float mL[4], mH[4], lLs[4], lHs[4];
#pragma unroll
    for (int r = 0; r < 4; r++) { mL[r] = mH[r] = -INFINITY; lLs[r] = lHs[r] = 0.f; }

    bf16x8 kreg[2], vreg[2];
#pragma unroll
    for (int i = 0; i < 2; i++) {
        int row = srow + i * 32;
        kreg[i] = *reinterpret_cast<const bf16x8*>(Kb + (size_t)row * HD + scolu);
        vreg[i] = *reinterpret_cast<const bf16x8*>(Vb + (size_t)row * S_ + scolu);
    }
#pragma unroll
    for (int i = 0; i < 2; i++) {
        int row = srow + i * 32;
        *reinterpret_cast<bf16x8*>(&Ksh[0][row * 72 + scolu]) = kreg[i];
        *reinterpret_cast<bf16x8*>(&Vsh[0][row * 72 + scolu]) = vreg[i];
    }
    __syncthreads();

    int cur = 0;
    for (int kv0 = 0; kv0 < endBlk; kv0 += 64) {
        const bool more = (kv0 + 64) < endBlk;
        if (more) {
#pragma unroll
            for (int i = 0; i < 2; i++) {
                int row = srow + i * 32;
                kreg[i] = *reinterpret_cast<const bf16x8*>(Kb + (size_t)(kv0 + 64 + row) * HD + scolu);
                vreg[i] = *reinterpret_cast<const bf16x8*>(Vb + (size_t)row * S_ + kv0 + 64 + scolu);
            }
        }
        const bool doL = kv0 < endL;
        const unsigned short* Kc = Ksh[cur];
        const unsigned short* Vc = Vsh[cur];

        float pH[4][4], pL[4][4];
#pragma unroll
        for (int kt = 0; kt < 4; kt++) {
            const int row = kt * 16 + lr;
            const int krow = kv0 + row;
            const bf16x8 bk0 = *reinterpret_cast<const bf16x8*>(&Kc[row * 72 + lc * 8]);
            const bf16x8 bk1 = *reinterpret_cast<const bf16x8*>(&Kc[row * 72 + 32 + lc * 8]);
            f32x4 sH = {};
            sH = __builtin_amdgcn_mfma_f32_16x16x32_bf16(aqH[0], bk0, sH, 0, 0, 0);
            sH = __builtin_amdgcn_mfma_f32_16x16x32_bf16(aqH[1], bk1, sH, 0, 0, 0);
#pragma unroll
            for (int r = 0; r < 4; r++) {
                float s = sH[r] * 0.125f;
                if (krow > qH + lc * 4 + r) s = -1e30f;
                pH[kt][r] = s;
            }
            if (doL) {
                f32x4 sL = {};
                sL = __builtin_amdgcn_mfma_f32_16x16x32_bf16(aqL[0], bk0, sL, 0, 0, 0);
                sL = __builtin_amdgcn_mfma_f32_16x16x32_bf16(aqL[1], bk1, sL, 0, 0, 0);
#pragma unroll
                for (int r = 0; r < 4; r++) {
                    float s = sL[r] * 0.125f;
                    if (krow > qL + lc * 4 + r) s = -1e30f;
                    pL[kt][r] = s;
                }
            }
        }

        float rmH[4], rmL[4];
#pragma unroll
        for (int r = 0; r < 4; r++) {
            rmH[r] = fmaxf(fmaxf(pH[0][r], pH[1][r]), fmaxf(pH[2][r], pH[3][r]));
            if (doL) rmL[r] = fmaxf(fmaxf(pL[0][r], pL[1][r]), fmaxf(pL[2][r], pL[3][r]));
        }
#pragma unroll
        for (int off = 1; off < 16; off <<= 1)
#pragma unroll
            for (int r = 0; r < 4; r++) {
                rmH[r] = fmaxf(rmH[r], __shfl_xor(rmH[r], off));
                if (doL) rmL[r] = fmaxf(rmL[r], __shfl_xor(rmL[r], off));
            }

        float rsH[4], rsL[4];
#pragma unroll
        for (int r = 0; r < 4; r++) {
            float mn = fmaxf(mH[r], rmH[r]);
            float sc = __expf(mH[r] - mn);
            float rs = 0.f;
#pragma unroll
            for (int kt = 0; kt < 4; kt++) {
                float e = __expf(pH[kt][r] - mn);
                pH[kt][r] = e; rs += e;
            }
            rsH[r] = rs; mH[r] = mn; lHs[r] *= sc;
#pragma unroll
            for (int dt = 0; dt < 4; dt++) oH[dt][r] *= sc;
            if (doL) {
                float mnl = fmaxf(mL[r], rmL[r]);
                float scl = __expf(mL[r] - mnl);
                float rsl = 0.f;
#pragma unroll
                for (int kt = 0; kt < 4; kt++) {
                    float e = __expf(pL[kt][r] - mnl);
                    pL[kt][r] = e; rsl += e;
                }
                rsL[r] = rsl; mL[r] = mnl; lLs[r] *= scl;
#pragma unroll
                for (int dt = 0; dt < 4; dt++) oL[dt][r] *= scl;
            }
        }
#pragma unroll
        for (int off = 1; off < 16; off <<= 1)
#pragma unroll
            for (int r = 0; r < 4; r++) {
                rsH[r] += __shfl_xor(rsH[r], off);
                if (doL) rsL[r] += __shfl_xor(rsL[r], off);
            }
#pragma unroll
        for (int r = 0; r < 4; r++) {
            lHs[r] += rsH[r];
            if (doL) lLs[r] += rsL[r];
        }

        // P -> LDS (transpose to A-fragment layout)
#pragma unroll
        for (int kt = 0; kt < 4; kt++)
#pragma unroll
            for (int r = 0; r < 4; r++) {
                Pl[w][0][lc * 4 + r][kt * 16 + lr] = f2bf(pH[kt][r]);
                if (doL) Pl[w][1][lc * 4 + r][kt * 16 + lr] = f2bf(pL[kt][r]);
            }
        asm volatile("s_waitcnt lgkmcnt(0)" ::: "memory");

        bf16x8 apH[2], apL[2];
#pragma unroll
        for (int kc = 0; kc < 2; kc++) {
            apH[kc] = *reinterpret_cast<const bf16x8*>(&Pl[w][0][lr][kc * 32 + lc * 8]);
            if (doL) apL[kc] = *reinterpret_cast<const bf16x8*>(&Pl[w][1][lr][kc * 32 + lc * 8]);
        }

#pragma unroll
        for (int dt = 0; dt < 4; dt++) {
            const int row = dt * 16 + lr;
#pragma unroll
            for (int kc = 0; kc < 2; kc++) {
                const bf16x8 bv = *reinterpret_cast<const bf16x8*>(
                    &Vc[row * 72 + kc * 32 + lc * 8]);
                oH[dt] = __builtin_amdgcn_mfma_f32_16x16x32_bf16(apH[kc], bv, oH[dt], 0, 0, 0);
                if (doL) oL[dt] = __builtin_amdgcn_mfma_f32_16x16x32_bf16(apL[kc], bv, oL[dt], 0, 0, 0);
            }
        }

        if (more) {
#pragma unroll
            for (int i = 0; i < 2; i++) {
                int row = srow + i * 32;
                *reinterpret_cast<bf16x8*>(&Ksh[cur ^ 1][row * 72 + scolu]) = kreg[i];
                *reinterpret_cast<bf16x8*>(&Vsh[cur ^ 1][row * 72 + scolu]) = vreg[i];
            }
        }
        __syncthreads();
        cur ^= 1;
    }

    int bb = bh / HEADS, h = bh - bb * HEADS;
#pragma unroll
    for (int r = 0; r < 4; r++) {
        float invH = 1.f / lHs[r], invL = 1.f / lLs[r];
        int qrH = qH + lc * 4 + r, qrL = qL + lc * 4 + r;
#pragma unroll
        for (int dt = 0; dt < 4; dt++) {
            int col = h * HD + dt * 16 + lr;
            O[((size_t)(bb * S_ + qrH)) * E_ + col] = f2bf(oH[dt][r] * invH);
            O[((size_t)(bb * S_ + qrL)) * E_ + col] = f2bf(oL[dt][r] * invL);
        }
    }
}

extern "C" void kernel_launch(void* const* d_in, const int* in_sizes, int n_in,
                              void* d_out, int out_size, void* d_ws, size_t ws_size,
                              hipStream_t stream) {
    const float* x      = (const float*)d_in[0];
    const float* w_attn = (const float*)d_in[1];
    const float* b_attn = (const float*)d_in[2];
    const float* w_proj = (const float*)d_in[3];
    const float* b_proj = (const float*)d_in[4];
    float* out = (float*)d_out;

    char* ws = (char*)d_ws;
    const size_t M = (size_t)B_ * S_;             // 8192
    unsigned short* xb  = (unsigned short*)(ws);                         // 8192*768
    unsigned short* waT = (unsigned short*)(ws + 12582912);              // 2304*768
    unsigned short* wpT = (unsigned short*)(ws + 16121856);              // 768*768
    unsigned short* Qb  = (unsigned short*)(ws + 17301504);              // BH*S*D
    unsigned short* Kb  = (unsigned short*)(ws + 29884416);
    unsigned short* Vt  = (unsigned short*)(ws + 42467328);
    unsigned short* AO  = (unsigned short*)(ws + 55050240);              // 8192*768

    int n4 = (int)(M * E_ / 4);
    cvt_kernel<<<(n4 + 255) / 256, 256, 0, stream>>>(x, xb, n4);
    transpose_cvt<<<dim3(3 * E_ / 32, E_ / 32), dim3(32, 32), 0, stream>>>(w_attn, waT, E_, 3 * E_);
    transpose_cvt<<<dim3(E_ / 32, E_ / 32), dim3(32, 32), 0, stream>>>(w_proj, wpT, E_, E_);

    gemm16<0><<<dim3(3 * E_ / 128, M / 128), 256, 0, stream>>>(
        xb, waT, b_attn, Qb, Kb, Vt, nullptr, (int)M, 3 * E_, E_);

    attn_kernel<<<dim3(16, B_ * HEADS), 256, 0, stream>>>(Qb, Kb, Vt, AO);

    gemm16<1><<<dim3(E_ / 128, M / 128), 256, 0, stream>>>(
        AO, wpT, b_proj, nullptr, nullptr, nullptr, out, (int)M, E_, E_);
}

// Round 7
// 304.596 us; speedup vs baseline: 1.7580x; 1.2636x over previous
//
#include <hip/hip_runtime.h>
#include <hip/hip_bf16.h>

typedef __attribute__((ext_vector_type(8))) __bf16 bf16x8;
typedef __attribute__((ext_vector_type(4))) float f32x4;

#define E_ 768
#define HEADS 12
#define HD 64
#define S_ 2048
#define B_ 4

__device__ inline unsigned short f2bf(float f) {
    union { float f; unsigned int u; } x{f};
    unsigned int r = x.u + 0x7FFFu + ((x.u >> 16) & 1u);
    return (unsigned short)(r >> 16);
}

// ---------- fp32 -> bf16 elementwise (x) ----------
__global__ void cvt_kernel(const float* __restrict__ in, unsigned short* __restrict__ out, int n4) {
    int i = blockIdx.x * blockDim.x + threadIdx.x;
    if (i < n4) {
        float4 v = reinterpret_cast<const float4*>(in)[i];
        ushort4 o;
        o.x = f2bf(v.x); o.y = f2bf(v.y); o.z = f2bf(v.z); o.w = f2bf(v.w);
        reinterpret_cast<ushort4*>(out)[i] = o;
    }
}

// ---------- transpose + convert: w[K][N] fp32 -> wT[N][K] bf16 ----------
__global__ void transpose_cvt(const float* __restrict__ w, unsigned short* __restrict__ wT,
                              int K, int N) {
    __shared__ float tile[32][33];
    int n0 = blockIdx.x * 32, k0 = blockIdx.y * 32;
    int tx = threadIdx.x, ty = threadIdx.y;
    tile[ty][tx] = w[(size_t)(k0 + ty) * N + n0 + tx];
    __syncthreads();
    wT[(size_t)(n0 + ty) * K + k0 + tx] = f2bf(tile[tx][ty]);
}

// ---------- bf16 MFMA GEMM: A[M][K] x Bt[N][K]^T, 128x128 block tile ----------
template<int MODE>
__global__ __launch_bounds__(256) void gemm16(
    const unsigned short* __restrict__ A, const unsigned short* __restrict__ Bt,
    const float* __restrict__ bias,
    unsigned short* __restrict__ Qo, unsigned short* __restrict__ Ko,
    unsigned short* __restrict__ Vt, float* __restrict__ Of,
    int M, int N, int K)
{
    int w = threadIdx.x >> 6, lane = threadIdx.x & 63;
    int lr = lane & 15, lc = lane >> 4;
    int row0 = blockIdx.y * 128 + (w >> 1) * 64;
    int col0 = blockIdx.x * 128 + (w & 1) * 64;

    f32x4 acc[4][4] = {};
    const unsigned short* Ap = A + (size_t)row0 * K + lc * 8;
    const unsigned short* Bp = Bt + (size_t)col0 * K + lc * 8;

    for (int k = 0; k < K; k += 32) {
        bf16x8 a[4], b[4];
#pragma unroll
        for (int i = 0; i < 4; i++)
            a[i] = *reinterpret_cast<const bf16x8*>(Ap + (size_t)(i * 16 + lr) * K + k);
#pragma unroll
        for (int j = 0; j < 4; j++)
            b[j] = *reinterpret_cast<const bf16x8*>(Bp + (size_t)(j * 16 + lr) * K + k);
#pragma unroll
        for (int i = 0; i < 4; i++)
#pragma unroll
            for (int j = 0; j < 4; j++)
                acc[i][j] = __builtin_amdgcn_mfma_f32_16x16x32_bf16(a[i], b[j], acc[i][j], 0, 0, 0);
    }

#pragma unroll
    for (int i = 0; i < 4; i++)
#pragma unroll
        for (int j = 0; j < 4; j++) {
            int col = col0 + j * 16 + lr;
            float bv = bias[col];
#pragma unroll
            for (int r = 0; r < 4; r++) {
                int row = row0 + i * 16 + lc * 4 + r;
                float val = acc[i][j][r] + bv;
                if constexpr (MODE == 0) {
                    int bb = row >> 11, s = row & (S_ - 1);
                    int which = col / E_;
                    int nn = col - which * E_;
                    int h = nn >> 6, d = nn & 63;
                    size_t bh = (size_t)(bb * HEADS + h);
                    if (which == 0)      Qo[(bh * S_ + s) * HD + d] = f2bf(val);
                    else if (which == 1) Ko[(bh * S_ + s) * HD + d] = f2bf(val);
                    else                 Vt[(bh * HD + d) * S_ + s] = f2bf(val);
                } else {
                    Of[(size_t)row * N + col] = val;
                }
            }
        }
}

// ---------- causal flash attention ----------
// grid: 768 blocks (bp = g/48 in 0..15, bh = g%48), block 256 = 4 waves.
// Block bp owns q-tiles tTL=bp and tTH=31-bp, run SEQUENTIALLY: light tile's
// kv loop (tTL+1 iters) then heavy's (tTH+1 iters) = 33 iters for EVERY
// block (uniform work, zero drain). One 64x64 K/V tile staged per iter in
// single-buffered, XOR-swizzled LDS (16B-slot ^ row&7, both sides).
// Softmax math is R6's verified version (expf/0.125/-1e30/-INF), untouched.
__global__ __launch_bounds__(256) void attn_kernel(
    const unsigned short* __restrict__ Q, const unsigned short* __restrict__ Kd,
    const unsigned short* __restrict__ Vt, unsigned short* __restrict__ O)
{
    __shared__ unsigned short Ksh[64 * 64];
    __shared__ unsigned short Vsh[64 * 64];
    __shared__ unsigned short Pl[4][16 * 64];

    const int t = threadIdx.x;
    const int w = t >> 6, lane = t & 63;
    const int lr = lane & 15, lc = lane >> 4;
    const int g = blockIdx.x;
    const int bp = g / 48;
    const int bh = g - bp * 48;
    const int tTL = bp, tTH = 31 - bp;
    const int qLrow0 = tTL * 64 + w * 16;
    const int qHrow0 = tTH * 64 + w * 16;

    const unsigned short* Qb = Q + (size_t)bh * S_ * HD;
    const unsigned short* Kb = Kd + (size_t)bh * S_ * HD;
    const unsigned short* Vb = Vt + (size_t)bh * HD * S_;

    // staging: thread t covers tile rows srow, srow+32; 16B slot (t&7)
    const int srow = t >> 3;
    const int scol = (t & 7) * 8;
    const int swz0 = srow * 64 + (((t & 7) ^ (srow & 7)) << 3);
    const int swz1 = swz0 + 32 * 64;   // (srow+32)&7 == srow&7
    const int r7 = lr & 7;             // read-side row&7 for rows kt*16+lr

    bf16x8 aqL[2], aqH[2];
#pragma unroll
    for (int dc = 0; dc < 2; dc++) {
        aqL[dc] = *reinterpret_cast<const bf16x8*>(Qb + (size_t)(qLrow0 + lr) * HD + dc * 32 + lc * 8);
        aqH[dc] = *reinterpret_cast<const bf16x8*>(Qb + (size_t)(qHrow0 + lr) * HD + dc * 32 + lc * 8);
    }

    f32x4 o[4] = {};
    float m[4], l[4];
#pragma unroll
    for (int r = 0; r < 4; r++) { m[r] = -INFINITY; l[r] = 0.f; }

    int bb = bh / HEADS, hh = bh - bb * HEADS;
    float* outBase = nullptr; // unused; direct stores below

    // prologue: load tile kv0=0 (light phase start)
    bf16x8 kreg[2], vreg[2];
#pragma unroll
    for (int i = 0; i < 2; i++) {
        int row = srow + i * 32;
        kreg[i] = *reinterpret_cast<const bf16x8*>(Kb + (size_t)row * HD + scol);
        vreg[i] = *reinterpret_cast<const bf16x8*>(Vb + (size_t)row * S_ + scol);
    }

    bf16x8 aq0 = aqL[0], aq1 = aqL[1];
    int qb = qLrow0;
    int kv0 = 0;

    for (int it = 0; it < 33; ++it) {
        __syncthreads();   // previous compute done; LDS reusable
        *reinterpret_cast<bf16x8*>(&Ksh[swz0]) = kreg[0];
        *reinterpret_cast<bf16x8*>(&Ksh[swz1]) = kreg[1];
        *reinterpret_cast<bf16x8*>(&Vsh[swz0]) = vreg[0];
        *reinterpret_cast<bf16x8*>(&Vsh[swz1]) = vreg[1];
        __syncthreads();   // tile ready

        // issue next tile's loads (overlap with compute)
        if (it + 1 < 33) {
            int nkv0 = (it + 1 <= tTL) ? (it + 1) * 64 : (it - tTL) * 64;
#pragma unroll
            for (int i = 0; i < 2; i++) {
                int row = srow + i * 32;
                kreg[i] = *reinterpret_cast<const bf16x8*>(Kb + (size_t)(nkv0 + row) * HD + scol);
                vreg[i] = *reinterpret_cast<const bf16x8*>(Vb + (size_t)row * S_ + nkv0 + scol);
            }
        }

        // uniform phase switch: finalize light tile, reset for heavy
        if (it == tTL + 1) {
#pragma unroll
            for (int r = 0; r < 4; r++) {
                float inv = 1.f / l[r];
                int qr = qLrow0 + lc * 4 + r;
#pragma unroll
                for (int dt = 0; dt < 4; dt++)
                    O[((size_t)(bb * S_ + qr)) * E_ + hh * HD + dt * 16 + lr] = f2bf(o[dt][r] * inv);
                m[r] = -INFINITY; l[r] = 0.f;
#pragma unroll
                for (int dt = 0; dt < 4; dt++) o[dt][r] = 0.f;
            }
            aq0 = aqH[0]; aq1 = aqH[1];
            qb = qHrow0;
            kv0 = 0;
        }

        // ---- compute one 16x64 tile step (R6 math, swizzled LDS reads) ----
        float p[4][4];
#pragma unroll
        for (int kt = 0; kt < 4; kt++) {
            const int row = kt * 16 + lr;
            const bf16x8 bk0 = *reinterpret_cast<const bf16x8*>(&Ksh[row * 64 + ((lc ^ r7) << 3)]);
            const bf16x8 bk1 = *reinterpret_cast<const bf16x8*>(&Ksh[row * 64 + (((4 + lc) ^ r7) << 3)]);
            f32x4 s = {};
            s = __builtin_amdgcn_mfma_f32_16x16x32_bf16(aq0, bk0, s, 0, 0, 0);
            s = __builtin_amdgcn_mfma_f32_16x16x32_bf16(aq1, bk1, s, 0, 0, 0);
            const int krow = kv0 + row;
#pragma unroll
            for (int r = 0; r < 4; r++) {
                float sv = s[r] * 0.125f;
                if (krow > qb + lc * 4 + r) sv = -1e30f;
                p[kt][r] = sv;
            }
        }

        float rm[4];
#pragma unroll
        for (int r = 0; r < 4; r++)
            rm[r] = fmaxf(fmaxf(p[0][r], p[1][r]), fmaxf(p[2][r], p[3][r]));
#pragma unroll
        for (int off = 1; off < 16; off <<= 1)
#pragma unroll
            for (int r = 0; r < 4; r++)
                rm[r] = fmaxf(rm[r], __shfl_xor(rm[r], off));

        float rs[4];
#pragma unroll
        for (int r = 0; r < 4; r++) {
            float mn = fmaxf(m[r], rm[r]);
            float sc = __expf(m[r] - mn);
            float acc = 0.f;
#pragma unroll
            for (int kt = 0; kt < 4; kt++) {
                float e = __expf(p[kt][r] - mn);
                p[kt][r] = e; acc += e;
            }
            rs[r] = acc; m[r] = mn; l[r] *= sc;
#pragma unroll
            for (int dt = 0; dt < 4; dt++) o[dt][r] *= sc;
        }
#pragma unroll
        for (int off = 1; off < 16; off <<= 1)
#pragma unroll
            for (int r = 0; r < 4; r++)
                rs[r] += __shfl_xor(rs[r], off);
#pragma unroll
        for (int r = 0; r < 4; r++) l[r] += rs[r];

        // P -> LDS (transpose to A-fragment layout), swizzled
#pragma unroll
        for (int kt = 0; kt < 4; kt++)
#pragma unroll
            for (int r = 0; r < 4; r++) {
                int rr = lc * 4 + r;
                Pl[w][rr * 64 + (((2 * kt + (lr >> 3)) ^ (rr & 7)) << 3) + (lr & 7)] = f2bf(p[kt][r]);
            }
        asm volatile("s_waitcnt lgkmcnt(0)" ::: "memory");
        __builtin_amdgcn_sched_barrier(0);

        bf16x8 ap[2];
#pragma unroll
        for (int kc = 0; kc < 2; kc++)
            ap[kc] = *reinterpret_cast<const bf16x8*>(&Pl[w][lr * 64 + (((kc * 4 + lc) ^ r7) << 3)]);

#pragma unroll
        for (int dt = 0; dt < 4; dt++) {
            const int row = dt * 16 + lr;
#pragma unroll
            for (int kc = 0; kc < 2; kc++) {
                const bf16x8 bv = *reinterpret_cast<const bf16x8*>(
                    &Vsh[row * 64 + (((kc * 4 + lc) ^ r7) << 3)]);
                o[dt] = __builtin_amdgcn_mfma_f32_16x16x32_bf16(ap[kc], bv, o[dt], 0, 0, 0);
            }
        }

        kv0 += 64;
    }

    // finalize heavy tile
#pragma unroll
    for (int r = 0; r < 4; r++) {
        float inv = 1.f / l[r];
        int qr = qHrow0 + lc * 4 + r;
#pragma unroll
        for (int dt = 0; dt < 4; dt++)
            O[((size_t)(bb * S_ + qr)) * E_ + hh * HD + dt * 16 + lr] = f2bf(o[dt][r] * inv);
    }
}

extern "C" void kernel_launch(void* const* d_in, const int* in_sizes, int n_in,
                              void* d_out, int out_size, void* d_ws, size_t ws_size,
                              hipStream_t stream) {
    const float* x      = (const float*)d_in[0];
    const float* w_attn = (const float*)d_in[1];
    const float* b_attn = (const float*)d_in[2];
    const float* w_proj = (const float*)d_in[3];
    const float* b_proj = (const float*)d_in[4];
    float* out = (float*)d_out;

    char* ws = (char*)d_ws;
    const size_t M = (size_t)B_ * S_;             // 8192
    unsigned short* xb  = (unsigned short*)(ws);                         // 8192*768
    unsigned short* waT = (unsigned short*)(ws + 12582912);              // 2304*768
    unsigned short* wpT = (unsigned short*)(ws + 16121856);              // 768*768
    unsigned short* Qb  = (unsigned short*)(ws + 17301504);              // BH*S*D
    unsigned short* Kb  = (unsigned short*)(ws + 29884416);
    unsigned short* Vt  = (unsigned short*)(ws + 42467328);
    unsigned short* AO  = (unsigned short*)(ws + 55050240);              // 8192*768

    int n4 = (int)(M * E_ / 4);
    cvt_kernel<<<(n4 + 255) / 256, 256, 0, stream>>>(x, xb, n4);
    transpose_cvt<<<dim3(3 * E_ / 32, E_ / 32), dim3(32, 32), 0, stream>>>(w_attn, waT, E_, 3 * E_);
    transpose_cvt<<<dim3(E_ / 32, E_ / 32), dim3(32, 32), 0, stream>>>(w_proj, wpT, E_, E_);

    gemm16<0><<<dim3(3 * E_ / 128, M / 128), 256, 0, stream>>>(
        xb, waT, b_attn, Qb, Kb, Vt, nullptr, (int)M, 3 * E_, E_);

    attn_kernel<<<768, 256, 0, stream>>>(Qb, Kb, Vt, AO);

    gemm16<1><<<dim3(E_ / 128, M / 128), 256, 0, stream>>>(
        AO, wpT, b_proj, nullptr, nullptr, nullptr, out, (int)M, E_, E_);
}

// Round 8
// 225.493 us; speedup vs baseline: 2.3747x; 1.3508x over previous
//
#include <hip/hip_runtime.h>
#include <hip/hip_bf16.h>

typedef __attribute__((ext_vector_type(8))) __bf16 bf16x8;
typedef __attribute__((ext_vector_type(4))) float f32x4;

#define E_ 768
#define HEADS 12
#define HD 64
#define S_ 2048
#define B_ 4

__device__ inline unsigned short f2bf(float f) {
    union { float f; unsigned int u; } x{f};
    unsigned int r = x.u + 0x7FFFu + ((x.u >> 16) & 1u);
    return (unsigned short)(r >> 16);
}

// ---------- fp32 -> bf16 elementwise (x) ----------
__global__ void cvt_kernel(const float* __restrict__ in, unsigned short* __restrict__ out, int n4) {
    int i = blockIdx.x * blockDim.x + threadIdx.x;
    if (i < n4) {
        float4 v = reinterpret_cast<const float4*>(in)[i];
        ushort4 o;
        o.x = f2bf(v.x); o.y = f2bf(v.y); o.z = f2bf(v.z); o.w = f2bf(v.w);
        reinterpret_cast<ushort4*>(out)[i] = o;
    }
}

// ---------- transpose + convert: w[K][N] fp32 -> wT[N][K] bf16 ----------
__global__ void transpose_cvt(const float* __restrict__ w, unsigned short* __restrict__ wT,
                              int K, int N) {
    __shared__ float tile[32][33];
    int n0 = blockIdx.x * 32, k0 = blockIdx.y * 32;
    int tx = threadIdx.x, ty = threadIdx.y;
    tile[ty][tx] = w[(size_t)(k0 + ty) * N + n0 + tx];
    __syncthreads();
    wT[(size_t)(n0 + ty) * K + k0 + tx] = f2bf(tile[tx][ty]);
}

// ---------- bf16 MFMA GEMM, m97 structure ----------
// 128x128 tile, BK=64, single-buffered LDS, global_load_lds(16B) staging,
// 2 barriers per K-step, ds_read_b128 fragments, 32 MFMA / K-step / wave.
// MODE 0: qkv scatter epilogue (Q,K [BH][S][D]; V transposed [BH][D][S], bf16)
// MODE 1: fp32 output with bias
template<int MODE>
__global__ __launch_bounds__(256) void gemm16(
    const unsigned short* __restrict__ A, const unsigned short* __restrict__ Bt,
    const float* __restrict__ bias,
    unsigned short* __restrict__ Qo, unsigned short* __restrict__ Ko,
    unsigned short* __restrict__ Vt, float* __restrict__ Of,
    int M, int N, int K)
{
    __shared__ unsigned short Ash[128 * 64];
    __shared__ unsigned short Bsh[128 * 64];

    const int t = threadIdx.x;
    const int w = t >> 6, lane = t & 63;
    const int lr = lane & 15, lc = lane >> 4;
    const int row0 = blockIdx.y * 128;
    const int col0 = blockIdx.x * 128;
    const int wrow = (w >> 1) * 64;
    const int wcol = (w & 1) * 64;

    // staging: per issue j, wave w covers 8 rows [j*32+w*8, +8);
    // lane covers row +(lane>>3), 16B slot (lane&7)  (matches lds dest = base + lane*16)
    const int srow = lane >> 3;
    const int sslot = lane & 7;

    f32x4 acc[4][4] = {};

    for (int k0 = 0; k0 < K; k0 += 64) {
#pragma unroll
        for (int j = 0; j < 4; j++) {
            const int rbase = j * 32 + w * 8;
            const unsigned short* ga = A + (size_t)(row0 + rbase + srow) * K + k0 + sslot * 8;
            __builtin_amdgcn_global_load_lds(
                (const __attribute__((address_space(1))) void*)ga,
                (__attribute__((address_space(3))) void*)&Ash[rbase * 64], 16, 0, 0);
            const unsigned short* gb = Bt + (size_t)(col0 + rbase + srow) * K + k0 + sslot * 8;
            __builtin_amdgcn_global_load_lds(
                (const __attribute__((address_space(1))) void*)gb,
                (__attribute__((address_space(3))) void*)&Bsh[rbase * 64], 16, 0, 0);
        }
        __syncthreads();

#pragma unroll
        for (int ks = 0; ks < 2; ks++) {
            bf16x8 a[4], b[4];
#pragma unroll
            for (int i = 0; i < 4; i++)
                a[i] = *reinterpret_cast<const bf16x8*>(&Ash[(wrow + i * 16 + lr) * 64 + ks * 32 + lc * 8]);
#pragma unroll
            for (int j2 = 0; j2 < 4; j2++)
                b[j2] = *reinterpret_cast<const bf16x8*>(&Bsh[(wcol + j2 * 16 + lr) * 64 + ks * 32 + lc * 8]);
#pragma unroll
            for (int i = 0; i < 4; i++)
#pragma unroll
                for (int j2 = 0; j2 < 4; j2++)
                    acc[i][j2] = __builtin_amdgcn_mfma_f32_16x16x32_bf16(a[i], b[j2], acc[i][j2], 0, 0, 0);
        }
        __syncthreads();
    }

#pragma unroll
    for (int i = 0; i < 4; i++)
#pragma unroll
        for (int j = 0; j < 4; j++) {
            int col = col0 + wcol + j * 16 + lr;
            float bv = bias[col];
#pragma unroll
            for (int r = 0; r < 4; r++) {
                int row = row0 + wrow + i * 16 + lc * 4 + r;
                float val = acc[i][j][r] + bv;
                if constexpr (MODE == 0) {
                    int bb = row >> 11, s = row & (S_ - 1);
                    int which = col / E_;
                    int nn = col - which * E_;
                    int h = nn >> 6, d = nn & 63;
                    size_t bh = (size_t)(bb * HEADS + h);
                    if (which == 0)      Qo[(bh * S_ + s) * HD + d] = f2bf(val);
                    else if (which == 1) Ko[(bh * S_ + s) * HD + d] = f2bf(val);
                    else                 Vt[(bh * HD + d) * S_ + s] = f2bf(val);
                } else {
                    Of[(size_t)row * N + col] = val;
                }
            }
        }
}

// ---------- causal flash attention (unchanged from R7, verified) ----------
__global__ __launch_bounds__(256) void attn_kernel(
    const unsigned short* __restrict__ Q, const unsigned short* __restrict__ Kd,
    const unsigned short* __restrict__ Vt, unsigned short* __restrict__ O)
{
    __shared__ unsigned short Ksh[64 * 64];
    __shared__ unsigned short Vsh[64 * 64];
    __shared__ unsigned short Pl[4][16 * 64];

    const int t = threadIdx.x;
    const int w = t >> 6, lane = t & 63;
    const int lr = lane & 15, lc = lane >> 4;
    const int g = blockIdx.x;
    const int bp = g / 48;
    const int bh = g - bp * 48;
    const int tTL = bp, tTH = 31 - bp;
    const int qLrow0 = tTL * 64 + w * 16;
    const int qHrow0 = tTH * 64 + w * 16;

    const unsigned short* Qb = Q + (size_t)bh * S_ * HD;
    const unsigned short* Kb = Kd + (size_t)bh * S_ * HD;
    const unsigned short* Vb = Vt + (size_t)bh * HD * S_;

    const int srow = t >> 3;
    const int scol = (t & 7) * 8;
    const int swz0 = srow * 64 + (((t & 7) ^ (srow & 7)) << 3);
    const int swz1 = swz0 + 32 * 64;
    const int r7 = lr & 7;

    bf16x8 aqL[2], aqH[2];
#pragma unroll
    for (int dc = 0; dc < 2; dc++) {
        aqL[dc] = *reinterpret_cast<const bf16x8*>(Qb + (size_t)(qLrow0 + lr) * HD + dc * 32 + lc * 8);
        aqH[dc] = *reinterpret_cast<const bf16x8*>(Qb + (size_t)(qHrow0 + lr) * HD + dc * 32 + lc * 8);
    }

    f32x4 o[4] = {};
    float m[4], l[4];
#pragma unroll
    for (int r = 0; r < 4; r++) { m[r] = -INFINITY; l[r] = 0.f; }

    int bb = bh / HEADS, hh = bh - bb * HEADS;

    bf16x8 kreg[2], vreg[2];
#pragma unroll
    for (int i = 0; i < 2; i++) {
        int row = srow + i * 32;
        kreg[i] = *reinterpret_cast<const bf16x8*>(Kb + (size_t)row * HD + scol);
        vreg[i] = *reinterpret_cast<const bf16x8*>(Vb + (size_t)row * S_ + scol);
    }

    bf16x8 aq0 = aqL[0], aq1 = aqL[1];
    int qb = qLrow0;
    int kv0 = 0;

    for (int it = 0; it < 33; ++it) {
        __syncthreads();
        *reinterpret_cast<bf16x8*>(&Ksh[swz0]) = kreg[0];
        *reinterpret_cast<bf16x8*>(&Ksh[swz1]) = kreg[1];
        *reinterpret_cast<bf16x8*>(&Vsh[swz0]) = vreg[0];
        *reinterpret_cast<bf16x8*>(&Vsh[swz1]) = vreg[1];
        __syncthreads();

        if (it + 1 < 33) {
            int nkv0 = (it + 1 <= tTL) ? (it + 1) * 64 : (it - tTL) * 64;
#pragma unroll
            for (int i = 0; i < 2; i++) {
                int row = srow + i * 32;
                kreg[i] = *reinterpret_cast<const bf16x8*>(Kb + (size_t)(nkv0 + row) * HD + scol);
                vreg[i] = *reinterpret_cast<const bf16x8*>(Vb + (size_t)row * S_ + nkv0 + scol);
            }
        }

        if (it == tTL + 1) {
#pragma unroll
            for (int r = 0; r < 4; r++) {
                float inv = 1.f / l[r];
                int qr = qLrow0 + lc * 4 + r;
#pragma unroll
                for (int dt = 0; dt < 4; dt++)
                    O[((size_t)(bb * S_ + qr)) * E_ + hh * HD + dt * 16 + lr] = f2bf(o[dt][r] * inv);
                m[r] = -INFINITY; l[r] = 0.f;
#pragma unroll
                for (int dt = 0; dt < 4; dt++) o[dt][r] = 0.f;
            }
            aq0 = aqH[0]; aq1 = aqH[1];
            qb = qHrow0;
            kv0 = 0;
        }

        float p[4][4];
#pragma unroll
        for (int kt = 0; kt < 4; kt++) {
            const int row = kt * 16 + lr;
            const bf16x8 bk0 = *reinterpret_cast<const bf16x8*>(&Ksh[row * 64 + ((lc ^ r7) << 3)]);
            const bf16x8 bk1 = *reinterpret_cast<const bf16x8*>(&Ksh[row * 64 + (((4 + lc) ^ r7) << 3)]);
            f32x4 s = {};
            s = __builtin_amdgcn_mfma_f32_16x16x32_bf16(aq0, bk0, s, 0, 0, 0);
            s = __builtin_amdgcn_mfma_f32_16x16x32_bf16(aq1, bk1, s, 0, 0, 0);
            const int krow = kv0 + row;
#pragma unroll
            for (int r = 0; r < 4; r++) {
                float sv = s[r] * 0.125f;
                if (krow > qb + lc * 4 + r) sv = -1e30f;
                p[kt][r] = sv;
            }
        }

        float rm[4];
#pragma unroll
        for (int r = 0; r < 4; r++)
            rm[r] = fmaxf(fmaxf(p[0][r], p[1][r]), fmaxf(p[2][r], p[3][r]));
#pragma unroll
        for (int off = 1; off < 16; off <<= 1)
#pragma unroll
            for (int r = 0; r < 4; r++)
                rm[r] = fmaxf(rm[r], __shfl_xor(rm[r], off));

        float rs[4];
#pragma unroll
        for (int r = 0; r < 4; r++) {
            float mn = fmaxf(m[r], rm[r]);
            float sc = __expf(m[r] - mn);
            float acc = 0.f;
#pragma unroll
            for (int kt = 0; kt < 4; kt++) {
                float e = __expf(p[kt][r] - mn);
                p[kt][r] = e; acc += e;
            }
            rs[r] = acc; m[r] = mn; l[r] *= sc;
#pragma unroll
            for (int dt = 0; dt < 4; dt++) o[dt][r] *= sc;
        }
#pragma unroll
        for (int off = 1; off < 16; off <<= 1)
#pragma unroll
            for (int r = 0; r < 4; r++)
                rs[r] += __shfl_xor(rs[r], off);
#pragma unroll
        for (int r = 0; r < 4; r++) l[r] += rs[r];

#pragma unroll
        for (int kt = 0; kt < 4; kt++)
#pragma unroll
            for (int r = 0; r < 4; r++) {
                int rr = lc * 4 + r;
                Pl[w][rr * 64 + (((2 * kt + (lr >> 3)) ^ (rr & 7)) << 3) + (lr & 7)] = f2bf(p[kt][r]);
            }
        asm volatile("s_waitcnt lgkmcnt(0)" ::: "memory");
        __builtin_amdgcn_sched_barrier(0);

        bf16x8 ap[2];
#pragma unroll
        for (int kc = 0; kc < 2; kc++)
            ap[kc] = *reinterpret_cast<const bf16x8*>(&Pl[w][lr * 64 + (((kc * 4 + lc) ^ r7) << 3)]);

#pragma unroll
        for (int dt = 0; dt < 4; dt++) {
            const int row = dt * 16 + lr;
#pragma unroll
            for (int kc = 0; kc < 2; kc++) {
                const bf16x8 bv = *reinterpret_cast<const bf16x8*>(
                    &Vsh[row * 64 + (((kc * 4 + lc) ^ r7) << 3)]);
                o[dt] = __builtin_amdgcn_mfma_f32_16x16x32_bf16(ap[kc], bv, o[dt], 0, 0, 0);
            }
        }

        kv0 += 64;
    }

#pragma unroll
    for (int r = 0; r < 4; r++) {
        float inv = 1.f / l[r];
        int qr = qHrow0 + lc * 4 + r;
#pragma unroll
        for (int dt = 0; dt < 4; dt++)
            O[((size_t)(bb * S_ + qr)) * E_ + hh * HD + dt * 16 + lr] = f2bf(o[dt][r] * inv);
    }
}

extern "C" void kernel_launch(void* const* d_in, const int* in_sizes, int n_in,
                              void* d_out, int out_size, void* d_ws, size_t ws_size,
                              hipStream_t stream) {
    const float* x      = (const float*)d_in[0];
    const float* w_attn = (const float*)d_in[1];
    const float* b_attn = (const float*)d_in[2];
    const float* w_proj = (const float*)d_in[3];
    const float* b_proj = (const float*)d_in[4];
    float* out = (float*)d_out;

    char* ws = (char*)d_ws;
    const size_t M = (size_t)B_ * S_;             // 8192
    unsigned short* xb  = (unsigned short*)(ws);                         // 8192*768
    unsigned short* waT = (unsigned short*)(ws + 12582912);              // 2304*768
    unsigned short* wpT = (unsigned short*)(ws + 16121856);              // 768*768
    unsigned short* Qb  = (unsigned short*)(ws + 17301504);              // BH*S*D
    unsigned short* Kb  = (unsigned short*)(ws + 29884416);
    unsigned short* Vt  = (unsigned short*)(ws + 42467328);
    unsigned short* AO  = (unsigned short*)(ws + 55050240);              // 8192*768

    int n4 = (int)(M * E_ / 4);
    cvt_kernel<<<(n4 + 255) / 256, 256, 0, stream>>>(x, xb, n4);
    transpose_cvt<<<dim3(3 * E_ / 32, E_ / 32), dim3(32, 32), 0, stream>>>(w_attn, waT, E_, 3 * E_);
    transpose_cvt<<<dim3(E_ / 32, E_ / 32), dim3(32, 32), 0, stream>>>(w_proj, wpT, E_, E_);

    gemm16<0><<<dim3(3 * E_ / 128, M / 128), 256, 0, stream>>>(
        xb, waT, b_attn, Qb, Kb, Vt, nullptr, (int)M, 3 * E_, E_);

    attn_kernel<<<768, 256, 0, stream>>>(Qb, Kb, Vt, AO);

    gemm16<1><<<dim3(E_ / 128, M / 128), 256, 0, stream>>>(
        AO, wpT, b_proj, nullptr, nullptr, nullptr, out, (int)M, E_, E_);
}

// Round 9
// 209.131 us; speedup vs baseline: 2.5605x; 1.0782x over previous
//
#include <hip/hip_runtime.h>
#include <hip/hip_bf16.h>

typedef __attribute__((ext_vector_type(8))) __bf16 bf16x8;
typedef __attribute__((ext_vector_type(4))) float f32x4;

#define E_ 768
#define HEADS 12
#define HD 64
#define S_ 2048
#define B_ 4

__device__ inline unsigned short f2bf(float f) {
    union { float f; unsigned int u; } x{f};
    unsigned int r = x.u + 0x7FFFu + ((x.u >> 16) & 1u);
    return (unsigned short)(r >> 16);
}

// ---------- fp32 -> bf16 elementwise (x) ----------
__global__ void cvt_kernel(const float* __restrict__ in, unsigned short* __restrict__ out, int n4) {
    int i = blockIdx.x * blockDim.x + threadIdx.x;
    if (i < n4) {
        float4 v = reinterpret_cast<const float4*>(in)[i];
        ushort4 o;
        o.x = f2bf(v.x); o.y = f2bf(v.y); o.z = f2bf(v.z); o.w = f2bf(v.w);
        reinterpret_cast<ushort4*>(out)[i] = o;
    }
}

// ---------- transpose + convert: w[K][N] fp32 -> wT[N][K] bf16 ----------
__global__ void transpose_cvt(const float* __restrict__ w, unsigned short* __restrict__ wT,
                              int K, int N) {
    __shared__ float tile[32][33];
    int n0 = blockIdx.x * 32, k0 = blockIdx.y * 32;
    int tx = threadIdx.x, ty = threadIdx.y;
    tile[ty][tx] = w[(size_t)(k0 + ty) * N + n0 + tx];
    __syncthreads();
    wT[(size_t)(n0 + ty) * K + k0 + tx] = f2bf(tile[tx][ty]);
}

// ---------- bf16 MFMA GEMM, m97 structure (unchanged from R8, verified) ----------
template<int MODE>
__global__ __launch_bounds__(256) void gemm16(
    const unsigned short* __restrict__ A, const unsigned short* __restrict__ Bt,
    const float* __restrict__ bias,
    unsigned short* __restrict__ Qo, unsigned short* __restrict__ Ko,
    unsigned short* __restrict__ Vt, float* __restrict__ Of,
    int M, int N, int K)
{
    __shared__ unsigned short Ash[128 * 64];
    __shared__ unsigned short Bsh[128 * 64];

    const int t = threadIdx.x;
    const int w = t >> 6, lane = t & 63;
    const int lr = lane & 15, lc = lane >> 4;
    const int row0 = blockIdx.y * 128;
    const int col0 = blockIdx.x * 128;
    const int wrow = (w >> 1) * 64;
    const int wcol = (w & 1) * 64;

    const int srow = lane >> 3;
    const int sslot = lane & 7;

    f32x4 acc[4][4] = {};

    for (int k0 = 0; k0 < K; k0 += 64) {
#pragma unroll
        for (int j = 0; j < 4; j++) {
            const int rbase = j * 32 + w * 8;
            const unsigned short* ga = A + (size_t)(row0 + rbase + srow) * K + k0 + sslot * 8;
            __builtin_amdgcn_global_load_lds(
                (const __attribute__((address_space(1))) void*)ga,
                (__attribute__((address_space(3))) void*)&Ash[rbase * 64], 16, 0, 0);
            const unsigned short* gb = Bt + (size_t)(col0 + rbase + srow) * K + k0 + sslot * 8;
            __builtin_amdgcn_global_load_lds(
                (const __attribute__((address_space(1))) void*)gb,
                (__attribute__((address_space(3))) void*)&Bsh[rbase * 64], 16, 0, 0);
        }
        __syncthreads();

#pragma unroll
        for (int ks = 0; ks < 2; ks++) {
            bf16x8 a[4], b[4];
#pragma unroll
            for (int i = 0; i < 4; i++)
                a[i] = *reinterpret_cast<const bf16x8*>(&Ash[(wrow + i * 16 + lr) * 64 + ks * 32 + lc * 8]);
#pragma unroll
            for (int j2 = 0; j2 < 4; j2++)
                b[j2] = *reinterpret_cast<const bf16x8*>(&Bsh[(wcol + j2 * 16 + lr) * 64 + ks * 32 + lc * 8]);
#pragma unroll
            for (int i = 0; i < 4; i++)
#pragma unroll
                for (int j2 = 0; j2 < 4; j2++)
                    acc[i][j2] = __builtin_amdgcn_mfma_f32_16x16x32_bf16(a[i], b[j2], acc[i][j2], 0, 0, 0);
        }
        __syncthreads();
    }

#pragma unroll
    for (int i = 0; i < 4; i++)
#pragma unroll
        for (int j = 0; j < 4; j++) {
            int col = col0 + wcol + j * 16 + lr;
            float bv = bias[col];
#pragma unroll
            for (int r = 0; r < 4; r++) {
                int row = row0 + wrow + i * 16 + lc * 4 + r;
                float val = acc[i][j][r] + bv;
                if constexpr (MODE == 0) {
                    int bb = row >> 11, s = row & (S_ - 1);
                    int which = col / E_;
                    int nn = col - which * E_;
                    int h = nn >> 6, d = nn & 63;
                    size_t bh = (size_t)(bb * HEADS + h);
                    if (which == 0)      Qo[(bh * S_ + s) * HD + d] = f2bf(val);
                    else if (which == 1) Ko[(bh * S_ + s) * HD + d] = f2bf(val);
                    else                 Vt[(bh * HD + d) * S_ + s] = f2bf(val);
                } else {
                    Of[(size_t)row * N + col] = val;
                }
            }
        }
}

// ---------- causal flash attention, KVBLK=128 ----------
// grid: 768 blocks (bp = g/48, bh = g%48), block 256 = 4 waves. Block bp owns
// q-tiles tTL=bp, tTH=31-bp run sequentially; 17 iterations of 128 kv for
// EVERY block (ceil((bp+1)/2)+ceil((32-bp)/2) == 17). Odd-tile overshoot is
// handled by the per-iteration causal mask. K[128][64] / V[64][128] / P tiles
// in XOR-swizzled LDS (physical slot = logical ^ row&mask, same involution
// both sides). Softmax math is R6's verified version, untouched.
__global__ __launch_bounds__(256) void attn_kernel(
    const unsigned short* __restrict__ Q, const unsigned short* __restrict__ Kd,
    const unsigned short* __restrict__ Vt, unsigned short* __restrict__ O)
{
    __shared__ unsigned short Ksh[128 * 64];
    __shared__ unsigned short Vsh[64 * 128];
    __shared__ unsigned short Pl[4][16 * 128];

    const int t = threadIdx.x;
    const int w = t >> 6, lane = t & 63;
    const int lr = lane & 15, lc = lane >> 4;
    const int g = blockIdx.x;
    const int bp = g / 48;
    const int bh = g - bp * 48;
    const int tTL = bp, tTH = 31 - bp;
    const int qLrow0 = tTL * 64 + w * 16;
    const int qHrow0 = tTH * 64 + w * 16;
    const int nL = (tTL + 2) >> 1;          // light-phase iterations (of 17)

    const unsigned short* Qb = Q + (size_t)bh * S_ * HD;
    const unsigned short* Kb = Kd + (size_t)bh * S_ * HD;
    const unsigned short* Vb = Vt + (size_t)bh * HD * S_;

    // K staging: rows srK+{0,32,64,96}, 16B slot ssK of 8 per 64-u16 row
    const int srK = t >> 3, ssK = t & 7;
    const int kws = ((ssK ^ (srK & 7)) << 3);     // swizzled col (u16)
    // V staging: rows srV+{0,16,32,48}, 16B slot ssV of 16 per 128-u16 row
    const int srV = t >> 4, ssV = t & 15;
    const int vws = ((ssV ^ (srV & 15)) << 3);
    const int r7 = lr & 7;

    bf16x8 aqL[2], aqH[2];
#pragma unroll
    for (int dc = 0; dc < 2; dc++) {
        aqL[dc] = *reinterpret_cast<const bf16x8*>(Qb + (size_t)(qLrow0 + lr) * HD + dc * 32 + lc * 8);
        aqH[dc] = *reinterpret_cast<const bf16x8*>(Qb + (size_t)(qHrow0 + lr) * HD + dc * 32 + lc * 8);
    }

    f32x4 o[4] = {};
    float m[4], l[4];
#pragma unroll
    for (int r = 0; r < 4; r++) { m[r] = -INFINITY; l[r] = 0.f; }

    int bb = bh / HEADS, hh = bh - bb * HEADS;

    // prologue: load light tile 0 (kv 0..127)
    bf16x8 kreg[4], vreg[4];
#pragma unroll
    for (int i = 0; i < 4; i++) {
        kreg[i] = *reinterpret_cast<const bf16x8*>(Kb + (size_t)(srK + i * 32) * HD + ssK * 8);
        vreg[i] = *reinterpret_cast<const bf16x8*>(Vb + (size_t)(srV + i * 16) * S_ + ssV * 8);
    }

    bf16x8 aq0 = aqL[0], aq1 = aqL[1];
    int qb = qLrow0;

    for (int it = 0; it < 17; ++it) {
        __syncthreads();   // previous compute done
#pragma unroll
        for (int i = 0; i < 4; i++) {
            *reinterpret_cast<bf16x8*>(&Ksh[(srK + i * 32) * 64 + kws]) = kreg[i];
            *reinterpret_cast<bf16x8*>(&Vsh[(srV + i * 16) * 128 + vws]) = vreg[i];
        }
        __syncthreads();   // tile ready

        if (it + 1 < 17) {
            int nkv0 = (it + 1 < nL) ? (it + 1) * 128 : (it + 1 - nL) * 128;
#pragma unroll
            for (int i = 0; i < 4; i++) {
                kreg[i] = *reinterpret_cast<const bf16x8*>(Kb + (size_t)(nkv0 + srK + i * 32) * HD + ssK * 8);
                vreg[i] = *reinterpret_cast<const bf16x8*>(Vb + (size_t)(srV + i * 16) * S_ + nkv0 + ssV * 8);
            }
        }

        // uniform phase switch: finalize light tile, reset for heavy
        if (it == nL) {
#pragma unroll
            for (int r = 0; r < 4; r++) {
                float inv = 1.f / l[r];
                int qr = qLrow0 + lc * 4 + r;
#pragma unroll
                for (int dt = 0; dt < 4; dt++)
                    O[((size_t)(bb * S_ + qr)) * E_ + hh * HD + dt * 16 + lr] = f2bf(o[dt][r] * inv);
                m[r] = -INFINITY; l[r] = 0.f;
#pragma unroll
                for (int dt = 0; dt < 4; dt++) o[dt][r] = 0.f;
            }
            aq0 = aqH[0]; aq1 = aqH[1];
            qb = qHrow0;
        }

        const int kv0 = (it < nL) ? it * 128 : (it - nL) * 128;

        // ---- QK^T: 8 kt subtiles of 16 kv ----
        float p[8][4];
#pragma unroll
        for (int kt = 0; kt < 8; kt++) {
            const int row = kt * 16 + lr;
            const bf16x8 bk0 = *reinterpret_cast<const bf16x8*>(&Ksh[row * 64 + ((lc ^ r7) << 3)]);
            const bf16x8 bk1 = *reinterpret_cast<const bf16x8*>(&Ksh[row * 64 + (((4 + lc) ^ r7) << 3)]);
            f32x4 s = {};
            s = __builtin_amdgcn_mfma_f32_16x16x32_bf16(aq0, bk0, s, 0, 0, 0);
            s = __builtin_amdgcn_mfma_f32_16x16x32_bf16(aq1, bk1, s, 0, 0, 0);
            const int krow = kv0 + row;
#pragma unroll
            for (int r = 0; r < 4; r++) {
                float sv = s[r] * 0.125f;
                if (krow > qb + lc * 4 + r) sv = -1e30f;
                p[kt][r] = sv;
            }
        }

        // ---- softmax (R6 math, kt width 8) ----
        float rm[4];
#pragma unroll
        for (int r = 0; r < 4; r++) {
            float a01 = fmaxf(p[0][r], p[1][r]), a23 = fmaxf(p[2][r], p[3][r]);
            float a45 = fmaxf(p[4][r], p[5][r]), a67 = fmaxf(p[6][r], p[7][r]);
            rm[r] = fmaxf(fmaxf(a01, a23), fmaxf(a45, a67));
        }
#pragma unroll
        for (int off = 1; off < 16; off <<= 1)
#pragma unroll
            for (int r = 0; r < 4; r++)
                rm[r] = fmaxf(rm[r], __shfl_xor(rm[r], off));

        float rs[4];
#pragma unroll
        for (int r = 0; r < 4; r++) {
            float mn = fmaxf(m[r], rm[r]);
            float sc = __expf(m[r] - mn);
            float acc = 0.f;
#pragma unroll
            for (int kt = 0; kt < 8; kt++) {
                float e = __expf(p[kt][r] - mn);
                p[kt][r] = e; acc += e;
            }
            rs[r] = acc; m[r] = mn; l[r] *= sc;
#pragma unroll
            for (int dt = 0; dt < 4; dt++) o[dt][r] *= sc;
        }
#pragma unroll
        for (int off = 1; off < 16; off <<= 1)
#pragma unroll
            for (int r = 0; r < 4; r++)
                rs[r] += __shfl_xor(rs[r], off);
#pragma unroll
        for (int r = 0; r < 4; r++) l[r] += rs[r];

        // ---- P -> LDS (transpose to A-fragment layout), swizzled ----
#pragma unroll
        for (int kt = 0; kt < 8; kt++) {
            const int slotc = kt * 2 + (lr >> 3);
#pragma unroll
            for (int r = 0; r < 4; r++) {
                const int rr = lc * 4 + r;
                Pl[w][rr * 128 + ((slotc ^ rr) << 3) + (lr & 7)] = f2bf(p[kt][r]);
            }
        }
        asm volatile("s_waitcnt lgkmcnt(0)" ::: "memory");
        __builtin_amdgcn_sched_barrier(0);

        bf16x8 ap[4];
#pragma unroll
        for (int kc = 0; kc < 4; kc++)
            ap[kc] = *reinterpret_cast<const bf16x8*>(&Pl[w][lr * 128 + (((kc * 4 + lc) ^ lr) << 3)]);

        // ---- PV ----
#pragma unroll
        for (int dt = 0; dt < 4; dt++) {
            const int row = dt * 16 + lr;
#pragma unroll
            for (int kc = 0; kc < 4; kc++) {
                const bf16x8 bv = *reinterpret_cast<const bf16x8*>(
                    &Vsh[row * 128 + (((kc * 4 + lc) ^ lr) << 3)]);
                o[dt] = __builtin_amdgcn_mfma_f32_16x16x32_bf16(ap[kc], bv, o[dt], 0, 0, 0);
            }
        }
    }

    // finalize heavy tile
#pragma unroll
    for (int r = 0; r < 4; r++) {
        float inv = 1.f / l[r];
        int qr = qHrow0 + lc * 4 + r;
#pragma unroll
        for (int dt = 0; dt < 4; dt++)
            O[((size_t)(bb * S_ + qr)) * E_ + hh * HD + dt * 16 + lr] = f2bf(o[dt][r] * inv);
    }
}

extern "C" void kernel_launch(void* const* d_in, const int* in_sizes, int n_in,
                              void* d_out, int out_size, void* d_ws, size_t ws_size,
                              hipStream_t stream) {
    const float* x      = (const float*)d_in[0];
    const float* w_attn = (const float*)d_in[1];
    const float* b_attn = (const float*)d_in[2];
    const float* w_proj = (const float*)d_in[3];
    const float* b_proj = (const float*)d_in[4];
    float* out = (float*)d_out;

    char* ws = (char*)d_ws;
    const size_t M = (size_t)B_ * S_;             // 8192
    unsigned short* xb  = (unsigned short*)(ws);                         // 8192*768
    unsigned short* waT = (unsigned short*)(ws + 12582912);              // 2304*768
    unsigned short* wpT = (unsigned short*)(ws + 16121856);              // 768*768
    unsigned short* Qb  = (unsigned short*)(ws + 17301504);              // BH*S*D
    unsigned short* Kb  = (unsigned short*)(ws + 29884416);
    unsigned short* Vt  = (unsigned short*)(ws + 42467328);
    unsigned short* AO  = (unsigned short*)(ws + 55050240);              // 8192*768

    int n4 = (int)(M * E_ / 4);
    cvt_kernel<<<(n4 + 255) / 256, 256, 0, stream>>>(x, xb, n4);
    transpose_cvt<<<dim3(3 * E_ / 32, E_ / 32), dim3(32, 32), 0, stream>>>(w_attn, waT, E_, 3 * E_);
    transpose_cvt<<<dim3(E_ / 32, E_ / 32), dim3(32, 32), 0, stream>>>(w_proj, wpT, E_, E_);

    gemm16<0><<<dim3(3 * E_ / 128, M / 128), 256, 0, stream>>>(
        xb, waT, b_attn, Qb, Kb, Vt, nullptr, (int)M, 3 * E_, E_);

    attn_kernel<<<768, 256, 0, stream>>>(Qb, Kb, Vt, AO);

    gemm16<1><<<dim3(E_ / 128, M / 128), 256, 0, stream>>>(
        AO, wpT, b_proj, nullptr, nullptr, nullptr, out, (int)M, E_, E_);
}

// Round 10
// 193.378 us; speedup vs baseline: 2.7691x; 1.0815x over previous
//
#include <hip/hip_runtime.h>
#include <hip/hip_bf16.h>

typedef __attribute__((ext_vector_type(8))) __bf16 bf16x8;
typedef __attribute__((ext_vector_type(4))) float f32x4;

#define E_ 768
#define HEADS 12
#define HD 64
#define S_ 2048
#define B_ 4

__device__ inline unsigned short f2bf(float f) {
    union { float f; unsigned int u; } x{f};
    unsigned int r = x.u + 0x7FFFu + ((x.u >> 16) & 1u);
    return (unsigned short)(r >> 16);
}

// ---------- fp32 -> bf16 elementwise (x) ----------
__global__ void cvt_kernel(const float* __restrict__ in, unsigned short* __restrict__ out, int n4) {
    int i = blockIdx.x * blockDim.x + threadIdx.x;
    if (i < n4) {
        float4 v = reinterpret_cast<const float4*>(in)[i];
        ushort4 o;
        o.x = f2bf(v.x); o.y = f2bf(v.y); o.z = f2bf(v.z); o.w = f2bf(v.w);
        reinterpret_cast<ushort4*>(out)[i] = o;
    }
}

// ---------- transpose + convert: w[K][N] fp32 -> wT[N][K] bf16 ----------
__global__ void transpose_cvt(const float* __restrict__ w, unsigned short* __restrict__ wT,
                              int K, int N) {
    __shared__ float tile[32][33];
    int n0 = blockIdx.x * 32, k0 = blockIdx.y * 32;
    int tx = threadIdx.x, ty = threadIdx.y;
    tile[ty][tx] = w[(size_t)(k0 + ty) * N + n0 + tx];
    __syncthreads();
    wT[(size_t)(n0 + ty) * K + k0 + tx] = f2bf(tile[tx][ty]);
}

// ---------- bf16 MFMA GEMM, m97 structure (unchanged, verified) ----------
template<int MODE>
__global__ __launch_bounds__(256) void gemm16(
    const unsigned short* __restrict__ A, const unsigned short* __restrict__ Bt,
    const float* __restrict__ bias,
    unsigned short* __restrict__ Qo, unsigned short* __restrict__ Ko,
    unsigned short* __restrict__ Vt, float* __restrict__ Of,
    int M, int N, int K)
{
    __shared__ unsigned short Ash[128 * 64];
    __shared__ unsigned short Bsh[128 * 64];

    const int t = threadIdx.x;
    const int w = t >> 6, lane = t & 63;
    const int lr = lane & 15, lc = lane >> 4;
    const int row0 = blockIdx.y * 128;
    const int col0 = blockIdx.x * 128;
    const int wrow = (w >> 1) * 64;
    const int wcol = (w & 1) * 64;

    const int srow = lane >> 3;
    const int sslot = lane & 7;

    f32x4 acc[4][4] = {};

    for (int k0 = 0; k0 < K; k0 += 64) {
#pragma unroll
        for (int j = 0; j < 4; j++) {
            const int rbase = j * 32 + w * 8;
            const unsigned short* ga = A + (size_t)(row0 + rbase + srow) * K + k0 + sslot * 8;
            __builtin_amdgcn_global_load_lds(
                (const __attribute__((address_space(1))) void*)ga,
                (__attribute__((address_space(3))) void*)&Ash[rbase * 64], 16, 0, 0);
            const unsigned short* gb = Bt + (size_t)(col0 + rbase + srow) * K + k0 + sslot * 8;
            __builtin_amdgcn_global_load_lds(
                (const __attribute__((address_space(1))) void*)gb,
                (__attribute__((address_space(3))) void*)&Bsh[rbase * 64], 16, 0, 0);
        }
        __syncthreads();

#pragma unroll
        for (int ks = 0; ks < 2; ks++) {
            bf16x8 a[4], b[4];
#pragma unroll
            for (int i = 0; i < 4; i++)
                a[i] = *reinterpret_cast<const bf16x8*>(&Ash[(wrow + i * 16 + lr) * 64 + ks * 32 + lc * 8]);
#pragma unroll
            for (int j2 = 0; j2 < 4; j2++)
                b[j2] = *reinterpret_cast<const bf16x8*>(&Bsh[(wcol + j2 * 16 + lr) * 64 + ks * 32 + lc * 8]);
#pragma unroll
            for (int i = 0; i < 4; i++)
#pragma unroll
                for (int j2 = 0; j2 < 4; j2++)
                    acc[i][j2] = __builtin_amdgcn_mfma_f32_16x16x32_bf16(a[i], b[j2], acc[i][j2], 0, 0, 0);
        }
        __syncthreads();
    }

#pragma unroll
    for (int i = 0; i < 4; i++)
#pragma unroll
        for (int j = 0; j < 4; j++) {
            int col = col0 + wcol + j * 16 + lr;
            float bv = bias[col];
#pragma unroll
            for (int r = 0; r < 4; r++) {
                int row = row0 + wrow + i * 16 + lc * 4 + r;
                float val = acc[i][j][r] + bv;
                if constexpr (MODE == 0) {
                    int bb = row >> 11, s = row & (S_ - 1);
                    int which = col / E_;
                    int nn = col - which * E_;
                    int h = nn >> 6, d = nn & 63;
                    size_t bh = (size_t)(bb * HEADS + h);
                    if (which == 0)      Qo[(bh * S_ + s) * HD + d] = f2bf(val);
                    else if (which == 1) Ko[(bh * S_ + s) * HD + d] = f2bf(val);
                    else                 Vt[(bh * HD + d) * S_ + s] = f2bf(val);
                } else {
                    Of[(size_t)row * N + col] = val;
                }
            }
        }
}

// ---------- causal flash attention, KVBLK=128, swapped QK^T ----------
// grid: 768 blocks (bp=g/48, bh=g%48), block 256 = 4 waves, 17 uniform iters.
// QK^T computed as mfma(K_frag, Q_frag): lane (lr,lc) owns S[q=q0+lr]
// [kv = kv0+kt*16+lc*4+r] -> row-softmax is in-lane(32) + 2 shfl rounds over
// the lc group; P->LDS is 8x ds_write_b64 (16B-pair swizzle ^(lr&7)).
// PV and output mapping unchanged. Softmax algebra is R6's frozen version.
__global__ __launch_bounds__(256) void attn_kernel(
    const unsigned short* __restrict__ Q, const unsigned short* __restrict__ Kd,
    const unsigned short* __restrict__ Vt, unsigned short* __restrict__ O)
{
    __shared__ unsigned short Ksh[128 * 64];
    __shared__ unsigned short Vsh[64 * 128];
    __shared__ unsigned short Pl[4][16 * 128];

    const int t = threadIdx.x;
    const int w = t >> 6, lane = t & 63;
    const int lr = lane & 15, lc = lane >> 4;
    const int g = blockIdx.x;
    const int bp = g / 48;
    const int bh = g - bp * 48;
    const int tTL = bp, tTH = 31 - bp;
    const int qLrow0 = tTL * 64 + w * 16;
    const int qHrow0 = tTH * 64 + w * 16;
    const int nL = (tTL + 2) >> 1;          // light-phase iterations (of 17)

    const unsigned short* Qb = Q + (size_t)bh * S_ * HD;
    const unsigned short* Kb = Kd + (size_t)bh * S_ * HD;
    const unsigned short* Vb = Vt + (size_t)bh * HD * S_;

    const int srK = t >> 3, ssK = t & 7;
    const int kws = ((ssK ^ (srK & 7)) << 3);
    const int srV = t >> 4, ssV = t & 15;
    const int vws = ((ssV ^ (srV & 15)) << 3);
    const int r7 = lr & 7;

    bf16x8 aqL[2], aqH[2];
#pragma unroll
    for (int dc = 0; dc < 2; dc++) {
        aqL[dc] = *reinterpret_cast<const bf16x8*>(Qb + (size_t)(qLrow0 + lr) * HD + dc * 32 + lc * 8);
        aqH[dc] = *reinterpret_cast<const bf16x8*>(Qb + (size_t)(qHrow0 + lr) * HD + dc * 32 + lc * 8);
    }

    f32x4 o[4] = {};
    float m = -INFINITY, l = 0.f;

    int bb = bh / HEADS, hh = bh - bb * HEADS;

    bf16x8 kreg[4], vreg[4];
#pragma unroll
    for (int i = 0; i < 4; i++) {
        kreg[i] = *reinterpret_cast<const bf16x8*>(Kb + (size_t)(srK + i * 32) * HD + ssK * 8);
        vreg[i] = *reinterpret_cast<const bf16x8*>(Vb + (size_t)(srV + i * 16) * S_ + ssV * 8);
    }

    bf16x8 aq0 = aqL[0], aq1 = aqL[1];
    int qrow = qLrow0 + lr;

    for (int it = 0; it < 17; ++it) {
        __syncthreads();
#pragma unroll
        for (int i = 0; i < 4; i++) {
            *reinterpret_cast<bf16x8*>(&Ksh[(srK + i * 32) * 64 + kws]) = kreg[i];
            *reinterpret_cast<bf16x8*>(&Vsh[(srV + i * 16) * 128 + vws]) = vreg[i];
        }
        __syncthreads();

        if (it + 1 < 17) {
            int nkv0 = (it + 1 < nL) ? (it + 1) * 128 : (it + 1 - nL) * 128;
#pragma unroll
            for (int i = 0; i < 4; i++) {
                kreg[i] = *reinterpret_cast<const bf16x8*>(Kb + (size_t)(nkv0 + srK + i * 32) * HD + ssK * 8);
                vreg[i] = *reinterpret_cast<const bf16x8*>(Vb + (size_t)(srV + i * 16) * S_ + nkv0 + ssV * 8);
            }
        }

        // uniform phase switch: finalize light tile, reset for heavy
        if (it == nL) {
            float lq[4];
#pragma unroll
            for (int r = 0; r < 4; r++) lq[r] = __shfl(l, lc * 4 + r);
#pragma unroll
            for (int r = 0; r < 4; r++) {
                float inv = 1.f / lq[r];
                int qr = qLrow0 + lc * 4 + r;
#pragma unroll
                for (int dt = 0; dt < 4; dt++)
                    O[((size_t)(bb * S_ + qr)) * E_ + hh * HD + dt * 16 + lr] = f2bf(o[dt][r] * inv);
            }
            m = -INFINITY; l = 0.f;
#pragma unroll
            for (int dt = 0; dt < 4; dt++)
#pragma unroll
                for (int r = 0; r < 4; r++) o[dt][r] = 0.f;
            aq0 = aqH[0]; aq1 = aqH[1];
            qrow = qHrow0 + lr;
        }

        const int kv0 = (it < nL) ? it * 128 : (it - nL) * 128;

        // ---- swapped QK^T: lane owns q=qrow, kv = kv0+kt*16+lc*4+r ----
        float p[8][4];
#pragma unroll
        for (int kt = 0; kt < 8; kt++) {
            const int row = kt * 16 + lr;
            const bf16x8 bk0 = *reinterpret_cast<const bf16x8*>(&Ksh[row * 64 + ((lc ^ r7) << 3)]);
            const bf16x8 bk1 = *reinterpret_cast<const bf16x8*>(&Ksh[row * 64 + (((4 + lc) ^ r7) << 3)]);
            f32x4 s = {};
            s = __builtin_amdgcn_mfma_f32_16x16x32_bf16(bk0, aq0, s, 0, 0, 0);
            s = __builtin_amdgcn_mfma_f32_16x16x32_bf16(bk1, aq1, s, 0, 0, 0);
            const int kbase = kv0 + kt * 16 + lc * 4;
#pragma unroll
            for (int r = 0; r < 4; r++) {
                float sv = s[r] * 0.125f;
                if (kbase + r > qrow) sv = -1e30f;
                p[kt][r] = sv;
            }
        }

        // ---- softmax (R6 algebra; in-lane + 2 shfl rounds) ----
        float rm = -1e30f;
#pragma unroll
        for (int kt = 0; kt < 8; kt++)
#pragma unroll
            for (int r = 0; r < 4; r++) rm = fmaxf(rm, p[kt][r]);
        rm = fmaxf(rm, __shfl_xor(rm, 16));
        rm = fmaxf(rm, __shfl_xor(rm, 32));

        float mn = fmaxf(m, rm);
        float sc = __expf(m - mn);
        float rs = 0.f;
#pragma unroll
        for (int kt = 0; kt < 8; kt++)
#pragma unroll
            for (int r = 0; r < 4; r++) {
                float e = __expf(p[kt][r] - mn);
                p[kt][r] = e; rs += e;
            }
        rs += __shfl_xor(rs, 16);
        rs += __shfl_xor(rs, 32);
        l = l * sc + rs;
        m = mn;

        float scq[4];
#pragma unroll
        for (int r = 0; r < 4; r++) scq[r] = __shfl(sc, lc * 4 + r);
#pragma unroll
        for (int dt = 0; dt < 4; dt++)
#pragma unroll
            for (int r = 0; r < 4; r++) o[dt][r] *= scq[r];

        // ---- P -> LDS: 8 x ds_write_b64, 16B-pair swizzle ^ (lr&7) ----
#pragma unroll
        for (int kt = 0; kt < 8; kt++) {
            unsigned int u0 = (unsigned)f2bf(p[kt][0]) | ((unsigned)f2bf(p[kt][1]) << 16);
            unsigned int u1 = (unsigned)f2bf(p[kt][2]) | ((unsigned)f2bf(p[kt][3]) << 16);
            const int phys = (2 * kt + (lc >> 1)) ^ r7;
            uint2 val; val.x = u0; val.y = u1;
            *reinterpret_cast<uint2*>(&Pl[w][lr * 128 + phys * 8 + (lc & 1) * 4]) = val;
        }
        asm volatile("s_waitcnt lgkmcnt(0)" ::: "memory");
        __builtin_amdgcn_sched_barrier(0);

        bf16x8 ap[4];
#pragma unroll
        for (int kc = 0; kc < 4; kc++)
            ap[kc] = *reinterpret_cast<const bf16x8*>(&Pl[w][lr * 128 + (((kc * 4 + lc) ^ r7) << 3)]);

        // ---- PV (unchanged) ----
#pragma unroll
        for (int dt = 0; dt < 4; dt++) {
            const int row = dt * 16 + lr;
#pragma unroll
            for (int kc = 0; kc < 4; kc++) {
                const bf16x8 bv = *reinterpret_cast<const bf16x8*>(
                    &Vsh[row * 128 + (((kc * 4 + lc) ^ lr) << 3)]);
                o[dt] = __builtin_amdgcn_mfma_f32_16x16x32_bf16(ap[kc], bv, o[dt], 0, 0, 0);
            }
        }
    }

    // finalize heavy tile
    {
        float lq[4];
#pragma unroll
        for (int r = 0; r < 4; r++) lq[r] = __shfl(l, lc * 4 + r);
#pragma unroll
        for (int r = 0; r < 4; r++) {
            float inv = 1.f / lq[r];
            int qr = qHrow0 + lc * 4 + r;
#pragma unroll
            for (int dt = 0; dt < 4; dt++)
                O[((size_t)(bb * S_ + qr)) * E_ + hh * HD + dt * 16 + lr] = f2bf(o[dt][r] * inv);
        }
    }
}

extern "C" void kernel_launch(void* const* d_in, const int* in_sizes, int n_in,
                              void* d_out, int out_size, void* d_ws, size_t ws_size,
                              hipStream_t stream) {
    const float* x      = (const float*)d_in[0];
    const float* w_attn = (const float*)d_in[1];
    const float* b_attn = (const float*)d_in[2];
    const float* w_proj = (const float*)d_in[3];
    const float* b_proj = (const float*)d_in[4];
    float* out = (float*)d_out;

    char* ws = (char*)d_ws;
    const size_t M = (size_t)B_ * S_;             // 8192
    unsigned short* xb  = (unsigned short*)(ws);                         // 8192*768
    unsigned short* waT = (unsigned short*)(ws + 12582912);              // 2304*768
    unsigned short* wpT = (unsigned short*)(ws + 16121856);              // 768*768
    unsigned short* Qb  = (unsigned short*)(ws + 17301504);              // BH*S*D
    unsigned short* Kb  = (unsigned short*)(ws + 29884416);
    unsigned short* Vt  = (unsigned short*)(ws + 42467328);
    unsigned short* AO  = (unsigned short*)(ws + 55050240);              // 8192*768

    int n4 = (int)(M * E_ / 4);
    cvt_kernel<<<(n4 + 255) / 256, 256, 0, stream>>>(x, xb, n4);
    transpose_cvt<<<dim3(3 * E_ / 32, E_ / 32), dim3(32, 32), 0, stream>>>(w_attn, waT, E_, 3 * E_);
    transpose_cvt<<<dim3(E_ / 32, E_ / 32), dim3(32, 32), 0, stream>>>(w_proj, wpT, E_, E_);

    gemm16<0><<<dim3(3 * E_ / 128, M / 128), 256, 0, stream>>>(
        xb, waT, b_attn, Qb, Kb, Vt, nullptr, (int)M, 3 * E_, E_);

    attn_kernel<<<768, 256, 0, stream>>>(Qb, Kb, Vt, AO);

    gemm16<1><<<dim3(E_ / 128, M / 128), 256, 0, stream>>>(
        AO, wpT, b_proj, nullptr, nullptr, nullptr, out, (int)M, E_, E_);
}

// Round 11
// 181.531 us; speedup vs baseline: 2.9499x; 1.0653x over previous
//
#include <hip/hip_runtime.h>
#include <hip/hip_bf16.h>

typedef __attribute__((ext_vector_type(8))) __bf16 bf16x8;
typedef __attribute__((ext_vector_type(4))) __bf16 bf16x4;
typedef __attribute__((ext_vector_type(4))) float f32x4;

#define E_ 768
#define HEADS 12
#define HD 64
#define S_ 2048
#define B_ 4

__device__ inline unsigned short f2bf(float f) {
    union { float f; unsigned int u; } x{f};
    unsigned int r = x.u + 0x7FFFu + ((x.u >> 16) & 1u);
    return (unsigned short)(r >> 16);
}

// ---------- fp32 -> bf16 elementwise (x) ----------
__global__ void cvt_kernel(const float* __restrict__ in, unsigned short* __restrict__ out, int n4) {
    int i = blockIdx.x * blockDim.x + threadIdx.x;
    if (i < n4) {
        float4 v = reinterpret_cast<const float4*>(in)[i];
        ushort4 o;
        o.x = f2bf(v.x); o.y = f2bf(v.y); o.z = f2bf(v.z); o.w = f2bf(v.w);
        reinterpret_cast<ushort4*>(out)[i] = o;
    }
}

// ---------- transpose + convert: w[K][N] fp32 -> wT[N][K] bf16 ----------
__global__ void transpose_cvt(const float* __restrict__ w, unsigned short* __restrict__ wT,
                              int K, int N) {
    __shared__ float tile[32][33];
    int n0 = blockIdx.x * 32, k0 = blockIdx.y * 32;
    int tx = threadIdx.x, ty = threadIdx.y;
    tile[ty][tx] = w[(size_t)(k0 + ty) * N + n0 + tx];
    __syncthreads();
    wT[(size_t)(n0 + ty) * K + k0 + tx] = f2bf(tile[tx][ty]);
}

// ---------- bf16 MFMA GEMM, m97 structure + XCD-chunked swizzle ----------
// 1D grid (nwg = (M/128)*(N/128), must be %8==0). Q outputs pre-scaled by
// 0.125 (folded softmax scale).
template<int MODE>
__global__ __launch_bounds__(256) void gemm16(
    const unsigned short* __restrict__ A, const unsigned short* __restrict__ Bt,
    const float* __restrict__ bias,
    unsigned short* __restrict__ Qo, unsigned short* __restrict__ Ko,
    unsigned short* __restrict__ Vt, float* __restrict__ Of,
    int M, int N, int K)
{
    __shared__ unsigned short Ash[128 * 64];
    __shared__ unsigned short Bsh[128 * 64];

    const int nbx = N >> 7;
    const int nwg = (M >> 7) * nbx;
    const int cpx = nwg >> 3;
    const int orig = blockIdx.x;
    const int wgid = (orig & 7) * cpx + (orig >> 3);   // XCD-chunked (nwg%8==0)
    const int row0 = (wgid / nbx) * 128;
    const int col0 = (wgid % nbx) * 128;

    const int t = threadIdx.x;
    const int w = t >> 6, lane = t & 63;
    const int lr = lane & 15, lc = lane >> 4;
    const int wrow = (w >> 1) * 64;
    const int wcol = (w & 1) * 64;

    const int srow = lane >> 3;
    const int sslot = lane & 7;

    f32x4 acc[4][4] = {};

    for (int k0 = 0; k0 < K; k0 += 64) {
#pragma unroll
        for (int j = 0; j < 4; j++) {
            const int rbase = j * 32 + w * 8;
            const unsigned short* ga = A + (size_t)(row0 + rbase + srow) * K + k0 + sslot * 8;
            __builtin_amdgcn_global_load_lds(
                (const __attribute__((address_space(1))) void*)ga,
                (__attribute__((address_space(3))) void*)&Ash[rbase * 64], 16, 0, 0);
            const unsigned short* gb = Bt + (size_t)(col0 + rbase + srow) * K + k0 + sslot * 8;
            __builtin_amdgcn_global_load_lds(
                (const __attribute__((address_space(1))) void*)gb,
                (__attribute__((address_space(3))) void*)&Bsh[rbase * 64], 16, 0, 0);
        }
        __syncthreads();

#pragma unroll
        for (int ks = 0; ks < 2; ks++) {
            bf16x8 a[4], b[4];
#pragma unroll
            for (int i = 0; i < 4; i++)
                a[i] = *reinterpret_cast<const bf16x8*>(&Ash[(wrow + i * 16 + lr) * 64 + ks * 32 + lc * 8]);
#pragma unroll
            for (int j2 = 0; j2 < 4; j2++)
                b[j2] = *reinterpret_cast<const bf16x8*>(&Bsh[(wcol + j2 * 16 + lr) * 64 + ks * 32 + lc * 8]);
#pragma unroll
            for (int i = 0; i < 4; i++)
#pragma unroll
                for (int j2 = 0; j2 < 4; j2++)
                    acc[i][j2] = __builtin_amdgcn_mfma_f32_16x16x32_bf16(a[i], b[j2], acc[i][j2], 0, 0, 0);
        }
        __syncthreads();
    }

#pragma unroll
    for (int i = 0; i < 4; i++)
#pragma unroll
        for (int j = 0; j < 4; j++) {
            int col = col0 + wcol + j * 16 + lr;
            float bv = bias[col];
#pragma unroll
            for (int r = 0; r < 4; r++) {
                int row = row0 + wrow + i * 16 + lc * 4 + r;
                float val = acc[i][j][r] + bv;
                if constexpr (MODE == 0) {
                    int bb = row >> 11, s = row & (S_ - 1);
                    int which = col / E_;
                    int nn = col - which * E_;
                    int h = nn >> 6, d = nn & 63;
                    size_t bh = (size_t)(bb * HEADS + h);
                    if (which == 0)      Qo[(bh * S_ + s) * HD + d] = f2bf(val * 0.125f);
                    else if (which == 1) Ko[(bh * S_ + s) * HD + d] = f2bf(val);
                    else                 Vt[(bh * HD + d) * S_ + s] = f2bf(val);
                } else {
                    Of[(size_t)row * N + col] = val;
                }
            }
        }
}

// ---------- causal flash attention, KVBLK=128, swapped QK^T ----------
// grid: 768 blocks (bp=g/48, bh=g%48), 4 waves, 17 uniform iters. Q comes
// pre-scaled by 0.125. Causal mask applied only on each phase's LAST
// iteration (proved: kv>q impossible earlier). P->bf16 via native casts
// (compiler emits cvt_pk). Softmax algebra is R6's frozen version.
__global__ __launch_bounds__(256) void attn_kernel(
    const unsigned short* __restrict__ Q, const unsigned short* __restrict__ Kd,
    const unsigned short* __restrict__ Vt, unsigned short* __restrict__ O)
{
    __shared__ unsigned short Ksh[128 * 64];
    __shared__ unsigned short Vsh[64 * 128];
    __shared__ unsigned short Pl[4][16 * 128];

    const int t = threadIdx.x;
    const int w = t >> 6, lane = t & 63;
    const int lr = lane & 15, lc = lane >> 4;
    const int g = blockIdx.x;
    const int bp = g / 48;
    const int bh = g - bp * 48;
    const int tTL = bp, tTH = 31 - bp;
    const int qLrow0 = tTL * 64 + w * 16;
    const int qHrow0 = tTH * 64 + w * 16;
    const int nL = (tTL + 2) >> 1;          // light-phase iterations (of 17)

    const unsigned short* Qb = Q + (size_t)bh * S_ * HD;
    const unsigned short* Kb = Kd + (size_t)bh * S_ * HD;
    const unsigned short* Vb = Vt + (size_t)bh * HD * S_;

    const int srK = t >> 3, ssK = t & 7;
    const int kws = ((ssK ^ (srK & 7)) << 3);
    const int srV = t >> 4, ssV = t & 15;
    const int vws = ((ssV ^ (srV & 15)) << 3);
    const int r7 = lr & 7;

    // hoisted staging bases (per-lane, loop-invariant)
    const unsigned short* KbS = Kb + (size_t)srK * HD + ssK * 8;
    const unsigned short* VbS = Vb + (size_t)srV * S_ + ssV * 8;

    bf16x8 aqL[2], aqH[2];
#pragma unroll
    for (int dc = 0; dc < 2; dc++) {
        aqL[dc] = *reinterpret_cast<const bf16x8*>(Qb + (size_t)(qLrow0 + lr) * HD + dc * 32 + lc * 8);
        aqH[dc] = *reinterpret_cast<const bf16x8*>(Qb + (size_t)(qHrow0 + lr) * HD + dc * 32 + lc * 8);
    }

    f32x4 o[4] = {};
    float m = -INFINITY, l = 0.f;

    int bb = bh / HEADS, hh = bh - bb * HEADS;

    bf16x8 kreg[4], vreg[4];
#pragma unroll
    for (int i = 0; i < 4; i++) {
        kreg[i] = *reinterpret_cast<const bf16x8*>(KbS + i * 32 * HD);
        vreg[i] = *reinterpret_cast<const bf16x8*>(VbS + i * 16 * S_);
    }

    bf16x8 aq0 = aqL[0], aq1 = aqL[1];
    int qrow = qLrow0 + lr;

    for (int it = 0; it < 17; ++it) {
        __syncthreads();
#pragma unroll
        for (int i = 0; i < 4; i++) {
            *reinterpret_cast<bf16x8*>(&Ksh[(srK + i * 32) * 64 + kws]) = kreg[i];
            *reinterpret_cast<bf16x8*>(&Vsh[(srV + i * 16) * 128 + vws]) = vreg[i];
        }
        __syncthreads();

        if (it + 1 < 17) {
            const int nkv0 = (it + 1 < nL) ? (it + 1) * 128 : (it + 1 - nL) * 128;
#pragma unroll
            for (int i = 0; i < 4; i++) {
                kreg[i] = *reinterpret_cast<const bf16x8*>(KbS + (size_t)nkv0 * HD + i * 32 * HD);
                vreg[i] = *reinterpret_cast<const bf16x8*>(VbS + nkv0 + i * 16 * S_);
            }
        }

        // uniform phase switch: finalize light tile, reset for heavy
        if (it == nL) {
            float lq[4];
#pragma unroll
            for (int r = 0; r < 4; r++) lq[r] = __shfl(l, lc * 4 + r);
#pragma unroll
            for (int r = 0; r < 4; r++) {
                float inv = 1.f / lq[r];
                int qr = qLrow0 + lc * 4 + r;
#pragma unroll
                for (int dt = 0; dt < 4; dt++)
                    O[((size_t)(bb * S_ + qr)) * E_ + hh * HD + dt * 16 + lr] = f2bf(o[dt][r] * inv);
            }
            m = -INFINITY; l = 0.f;
#pragma unroll
            for (int dt = 0; dt < 4; dt++)
#pragma unroll
                for (int r = 0; r < 4; r++) o[dt][r] = 0.f;
            aq0 = aqH[0]; aq1 = aqH[1];
            qrow = qHrow0 + lr;
        }

        const int kv0 = (it < nL) ? it * 128 : (it - nL) * 128;
        const bool needMask = (it == nL - 1) || (it == 16);

        // ---- swapped QK^T: lane owns q=qrow, kv = kv0+kt*16+lc*4+r ----
        float p[8][4];
#pragma unroll
        for (int kt = 0; kt < 8; kt++) {
            const int row = kt * 16 + lr;
            const bf16x8 bk0 = *reinterpret_cast<const bf16x8*>(&Ksh[row * 64 + ((lc ^ r7) << 3)]);
            const bf16x8 bk1 = *reinterpret_cast<const bf16x8*>(&Ksh[row * 64 + (((4 + lc) ^ r7) << 3)]);
            f32x4 s = {};
            s = __builtin_amdgcn_mfma_f32_16x16x32_bf16(bk0, aq0, s, 0, 0, 0);
            s = __builtin_amdgcn_mfma_f32_16x16x32_bf16(bk1, aq1, s, 0, 0, 0);
#pragma unroll
            for (int r = 0; r < 4; r++) p[kt][r] = s[r];
        }
        if (needMask) {
#pragma unroll
            for (int kt = 0; kt < 8; kt++) {
                const int kbase = kv0 + kt * 16 + lc * 4;
#pragma unroll
                for (int r = 0; r < 4; r++)
                    if (kbase + r > qrow) p[kt][r] = -1e30f;
            }
        }

        // ---- softmax (R6 algebra; in-lane + 2 shfl rounds) ----
        float rm = -1e30f;
#pragma unroll
        for (int kt = 0; kt < 8; kt++)
#pragma unroll
            for (int r = 0; r < 4; r++) rm = fmaxf(rm, p[kt][r]);
        rm = fmaxf(rm, __shfl_xor(rm, 16));
        rm = fmaxf(rm, __shfl_xor(rm, 32));

        float mn = fmaxf(m, rm);
        float sc = __expf(m - mn);
        float rs = 0.f;
#pragma unroll
        for (int kt = 0; kt < 8; kt++)
#pragma unroll
            for (int r = 0; r < 4; r++) {
                float e = __expf(p[kt][r] - mn);
                p[kt][r] = e; rs += e;
            }
        rs += __shfl_xor(rs, 16);
        rs += __shfl_xor(rs, 32);
        l = l * sc + rs;
        m = mn;

        float scq[4];
#pragma unroll
        for (int r = 0; r < 4; r++) scq[r] = __shfl(sc, lc * 4 + r);
#pragma unroll
        for (int dt = 0; dt < 4; dt++)
#pragma unroll
            for (int r = 0; r < 4; r++) o[dt][r] *= scq[r];

        // ---- P -> LDS: 8 x ds_write_b64, native bf16 casts (cvt_pk) ----
#pragma unroll
        for (int kt = 0; kt < 8; kt++) {
            bf16x4 pv4;
            pv4[0] = (__bf16)p[kt][0]; pv4[1] = (__bf16)p[kt][1];
            pv4[2] = (__bf16)p[kt][2]; pv4[3] = (__bf16)p[kt][3];
            const int phys = (2 * kt + (lc >> 1)) ^ r7;
            *reinterpret_cast<bf16x4*>(&Pl[w][lr * 128 + phys * 8 + (lc & 1) * 4]) = pv4;
        }
        asm volatile("s_waitcnt lgkmcnt(0)" ::: "memory");
        __builtin_amdgcn_sched_barrier(0);

        bf16x8 ap[4];
#pragma unroll
        for (int kc = 0; kc < 4; kc++)
            ap[kc] = *reinterpret_cast<const bf16x8*>(&Pl[w][lr * 128 + (((kc * 4 + lc) ^ r7) << 3)]);

        // ---- PV (unchanged) ----
#pragma unroll
        for (int dt = 0; dt < 4; dt++) {
            const int row = dt * 16 + lr;
#pragma unroll
            for (int kc = 0; kc < 4; kc++) {
                const bf16x8 bv = *reinterpret_cast<const bf16x8*>(
                    &Vsh[row * 128 + (((kc * 4 + lc) ^ lr) << 3)]);
                o[dt] = __builtin_amdgcn_mfma_f32_16x16x32_bf16(ap[kc], bv, o[dt], 0, 0, 0);
            }
        }
    }

    // finalize heavy tile
    {
        float lq[4];
#pragma unroll
        for (int r = 0; r < 4; r++) lq[r] = __shfl(l, lc * 4 + r);
#pragma unroll
        for (int r = 0; r < 4; r++) {
            float inv = 1.f / lq[r];
            int qr = qHrow0 + lc * 4 + r;
#pragma unroll
            for (int dt = 0; dt < 4; dt++)
                O[((size_t)(bb * S_ + qr)) * E_ + hh * HD + dt * 16 + lr] = f2bf(o[dt][r] * inv);
        }
    }
}

extern "C" void kernel_launch(void* const* d_in, const int* in_sizes, int n_in,
                              void* d_out, int out_size, void* d_ws, size_t ws_size,
                              hipStream_t stream) {
    const float* x      = (const float*)d_in[0];
    const float* w_attn = (const float*)d_in[1];
    const float* b_attn = (const float*)d_in[2];
    const float* w_proj = (const float*)d_in[3];
    const float* b_proj = (const float*)d_in[4];
    float* out = (float*)d_out;

    char* ws = (char*)d_ws;
    const size_t M = (size_t)B_ * S_;             // 8192
    unsigned short* xb  = (unsigned short*)(ws);                         // 8192*768
    unsigned short* waT = (unsigned short*)(ws + 12582912);              // 2304*768
    unsigned short* wpT = (unsigned short*)(ws + 16121856);              // 768*768
    unsigned short* Qb  = (unsigned short*)(ws + 17301504);              // BH*S*D
    unsigned short* Kb  = (unsigned short*)(ws + 29884416);
    unsigned short* Vt  = (unsigned short*)(ws + 42467328);
    unsigned short* AO  = (unsigned short*)(ws + 55050240);              // 8192*768

    int n4 = (int)(M * E_ / 4);
    cvt_kernel<<<(n4 + 255) / 256, 256, 0, stream>>>(x, xb, n4);
    transpose_cvt<<<dim3(3 * E_ / 32, E_ / 32), dim3(32, 32), 0, stream>>>(w_attn, waT, E_, 3 * E_);
    transpose_cvt<<<dim3(E_ / 32, E_ / 32), dim3(32, 32), 0, stream>>>(w_proj, wpT, E_, E_);

    gemm16<0><<<1152, 256, 0, stream>>>(
        xb, waT, b_attn, Qb, Kb, Vt, nullptr, (int)M, 3 * E_, E_);

    attn_kernel<<<768, 256, 0, stream>>>(Qb, Kb, Vt, AO);

    gemm16<1><<<384, 256, 0, stream>>>(
        AO, wpT, b_proj, nullptr, nullptr, nullptr, out, (int)M, E_, E_);
}

// Round 12
// 167.030 us; speedup vs baseline: 3.2060x; 1.0868x over previous
//
#include <hip/hip_runtime.h>
#include <hip/hip_bf16.h>

typedef __attribute__((ext_vector_type(8))) __bf16 bf16x8;
typedef __attribute__((ext_vector_type(4))) __bf16 bf16x4;
typedef __attribute__((ext_vector_type(4))) float f32x4;

#define E_ 768
#define HEADS 12
#define HD 64
#define S_ 2048
#define B_ 4

__device__ inline unsigned short f2bf(float f) {
    union { float f; unsigned int u; } x{f};
    unsigned int r = x.u + 0x7FFFu + ((x.u >> 16) & 1u);
    return (unsigned short)(r >> 16);
}

// ---------- fp32 -> bf16 elementwise (x) ----------
__global__ void cvt_kernel(const float* __restrict__ in, unsigned short* __restrict__ out, int n4) {
    int i = blockIdx.x * blockDim.x + threadIdx.x;
    if (i < n4) {
        float4 v = reinterpret_cast<const float4*>(in)[i];
        ushort4 o;
        o.x = f2bf(v.x); o.y = f2bf(v.y); o.z = f2bf(v.z); o.w = f2bf(v.w);
        reinterpret_cast<ushort4*>(out)[i] = o;
    }
}

// ---------- transpose + convert: w[K][N] fp32 -> wT[N][K] bf16 ----------
__global__ void transpose_cvt(const float* __restrict__ w, unsigned short* __restrict__ wT,
                              int K, int N) {
    __shared__ float tile[32][33];
    int n0 = blockIdx.x * 32, k0 = blockIdx.y * 32;
    int tx = threadIdx.x, ty = threadIdx.y;
    tile[ty][tx] = w[(size_t)(k0 + ty) * N + n0 + tx];
    __syncthreads();
    wT[(size_t)(n0 + ty) * K + k0 + tx] = f2bf(tile[tx][ty]);
}

// ---------- bf16 MFMA GEMM, m97 structure + XCD-chunked swizzle ----------
// MODE 0: qkv. Q pre-scaled 0.125. V blocks (col0>=1536) use an LDS-transpose
// epilogue -> coalesced 512B stores along S (fixes 2B/4KB-stride write amp).
// MODE 1: fp32 out + bias.
template<int MODE>
__global__ __launch_bounds__(256) void gemm16(
    const unsigned short* __restrict__ A, const unsigned short* __restrict__ Bt,
    const float* __restrict__ bias,
    unsigned short* __restrict__ Qo, unsigned short* __restrict__ Ko,
    unsigned short* __restrict__ Vt, float* __restrict__ Of,
    int M, int N, int K)
{
    __shared__ unsigned short Sh[128 * 128];   // Ash = Sh[0:8192), Bsh = Sh[8192:16384)
    unsigned short* Ash = Sh;
    unsigned short* Bsh = Sh + 128 * 64;

    const int nbx = N >> 7;
    const int nwg = (M >> 7) * nbx;
    const int cpx = nwg >> 3;
    const int orig = blockIdx.x;
    const int wgid = (orig & 7) * cpx + (orig >> 3);   // XCD-chunked (nwg%8==0)
    const int row0 = (wgid / nbx) * 128;
    const int col0 = (wgid % nbx) * 128;

    const int t = threadIdx.x;
    const int w = t >> 6, lane = t & 63;
    const int lr = lane & 15, lc = lane >> 4;
    const int wrow = (w >> 1) * 64;
    const int wcol = (w & 1) * 64;

    const int srow = lane >> 3;
    const int sslot = lane & 7;

    f32x4 acc[4][4] = {};

    for (int k0 = 0; k0 < K; k0 += 64) {
#pragma unroll
        for (int j = 0; j < 4; j++) {
            const int rbase = j * 32 + w * 8;
            const unsigned short* ga = A + (size_t)(row0 + rbase + srow) * K + k0 + sslot * 8;
            __builtin_amdgcn_global_load_lds(
                (const __attribute__((address_space(1))) void*)ga,
                (__attribute__((address_space(3))) void*)&Ash[rbase * 64], 16, 0, 0);
            const unsigned short* gb = Bt + (size_t)(col0 + rbase + srow) * K + k0 + sslot * 8;
            __builtin_amdgcn_global_load_lds(
                (const __attribute__((address_space(1))) void*)gb,
                (__attribute__((address_space(3))) void*)&Bsh[rbase * 64], 16, 0, 0);
        }
        __syncthreads();

#pragma unroll
        for (int ks = 0; ks < 2; ks++) {
            bf16x8 a[4], b[4];
#pragma unroll
            for (int i = 0; i < 4; i++)
                a[i] = *reinterpret_cast<const bf16x8*>(&Ash[(wrow + i * 16 + lr) * 64 + ks * 32 + lc * 8]);
#pragma unroll
            for (int j2 = 0; j2 < 4; j2++)
                b[j2] = *reinterpret_cast<const bf16x8*>(&Bsh[(wcol + j2 * 16 + lr) * 64 + ks * 32 + lc * 8]);
#pragma unroll
            for (int i = 0; i < 4; i++)
#pragma unroll
                for (int j2 = 0; j2 < 4; j2++)
                    acc[i][j2] = __builtin_amdgcn_mfma_f32_16x16x32_bf16(a[i], b[j2], acc[i][j2], 0, 0, 0);
        }
        __syncthreads();
    }

    if constexpr (MODE == 0) {
        if (col0 >= 2 * E_) {
            // ---- V block: LDS transpose -> coalesced V^T stores ----
            // stage C^T: Tr[c][row ^ ((c&15)<<3)]  (involution, keeps 16B chunks)
#pragma unroll
            for (int i = 0; i < 4; i++)
#pragma unroll
                for (int j = 0; j < 4; j++) {
                    const int c = wcol + j * 16 + lr;
                    const float bv = bias[col0 + c];
#pragma unroll
                    for (int r = 0; r < 4; r++) {
                        const int row = wrow + i * 16 + lc * 4 + r;
                        Sh[c * 128 + (row ^ ((c & 15) << 3))] = f2bf(acc[i][j][r] + bv);
                    }
                }
            __syncthreads();
            const int bb = row0 >> 11;
            const int s0 = row0 & (S_ - 1);
            const int nnb = col0 - 2 * E_;
#pragma unroll
            for (int pass = 0; pass < 8; pass++) {
                const int c = pass * 16 + (t >> 4);
                const int sL = (t & 15) * 8;
                bf16x8 vv = *reinterpret_cast<const bf16x8*>(&Sh[c * 128 + (sL ^ ((c & 15) << 3))]);
                const int h = (nnb + c) >> 6, d = c & 63;
                const size_t bh = (size_t)(bb * HEADS + h);
                *reinterpret_cast<bf16x8*>(&Vt[(bh * HD + d) * S_ + s0 + sL]) = vv;
            }
            return;
        }
        // ---- Q/K blocks: direct scatter (32B segments) ----
#pragma unroll
        for (int i = 0; i < 4; i++)
#pragma unroll
            for (int j = 0; j < 4; j++) {
                int col = col0 + wcol + j * 16 + lr;
                float bv = bias[col];
#pragma unroll
                for (int r = 0; r < 4; r++) {
                    int row = row0 + wrow + i * 16 + lc * 4 + r;
                    float val = acc[i][j][r] + bv;
                    int bb = row >> 11, s = row & (S_ - 1);
                    int which = col / E_;
                    int nn = col - which * E_;
                    int h = nn >> 6, d = nn & 63;
                    size_t bh = (size_t)(bb * HEADS + h);
                    if (which == 0)      Qo[(bh * S_ + s) * HD + d] = f2bf(val * 0.125f);
                    else                 Ko[(bh * S_ + s) * HD + d] = f2bf(val);
                }
            }
    } else {
#pragma unroll
        for (int i = 0; i < 4; i++)
#pragma unroll
            for (int j = 0; j < 4; j++) {
                int col = col0 + wcol + j * 16 + lr;
                float bv = bias[col];
#pragma unroll
                for (int r = 0; r < 4; r++) {
                    int row = row0 + wrow + i * 16 + lc * 4 + r;
                    Of[(size_t)row * N + col] = acc[i][j][r] + bv;
                }
            }
    }
}

// ---------- causal flash attention (unchanged from R11, verified) ----------
__global__ __launch_bounds__(256) void attn_kernel(
    const unsigned short* __restrict__ Q, const unsigned short* __restrict__ Kd,
    const unsigned short* __restrict__ Vt, unsigned short* __restrict__ O)
{
    __shared__ unsigned short Ksh[128 * 64];
    __shared__ unsigned short Vsh[64 * 128];
    __shared__ unsigned short Pl[4][16 * 128];

    const int t = threadIdx.x;
    const int w = t >> 6, lane = t & 63;
    const int lr = lane & 15, lc = lane >> 4;
    const int g = blockIdx.x;
    const int bp = g / 48;
    const int bh = g - bp * 48;
    const int tTL = bp, tTH = 31 - bp;
    const int qLrow0 = tTL * 64 + w * 16;
    const int qHrow0 = tTH * 64 + w * 16;
    const int nL = (tTL + 2) >> 1;

    const unsigned short* Qb = Q + (size_t)bh * S_ * HD;
    const unsigned short* Kb = Kd + (size_t)bh * S_ * HD;
    const unsigned short* Vb = Vt + (size_t)bh * HD * S_;

    const int srK = t >> 3, ssK = t & 7;
    const int kws = ((ssK ^ (srK & 7)) << 3);
    const int srV = t >> 4, ssV = t & 15;
    const int vws = ((ssV ^ (srV & 15)) << 3);
    const int r7 = lr & 7;

    const unsigned short* KbS = Kb + (size_t)srK * HD + ssK * 8;
    const unsigned short* VbS = Vb + (size_t)srV * S_ + ssV * 8;

    bf16x8 aqL[2], aqH[2];
#pragma unroll
    for (int dc = 0; dc < 2; dc++) {
        aqL[dc] = *reinterpret_cast<const bf16x8*>(Qb + (size_t)(qLrow0 + lr) * HD + dc * 32 + lc * 8);
        aqH[dc] = *reinterpret_cast<const bf16x8*>(Qb + (size_t)(qHrow0 + lr) * HD + dc * 32 + lc * 8);
    }

    f32x4 o[4] = {};
    float m = -INFINITY, l = 0.f;

    int bb = bh / HEADS, hh = bh - bb * HEADS;

    bf16x8 kreg[4], vreg[4];
#pragma unroll
    for (int i = 0; i < 4; i++) {
        kreg[i] = *reinterpret_cast<const bf16x8*>(KbS + i * 32 * HD);
        vreg[i] = *reinterpret_cast<const bf16x8*>(VbS + i * 16 * S_);
    }

    bf16x8 aq0 = aqL[0], aq1 = aqL[1];
    int qrow = qLrow0 + lr;

    for (int it = 0; it < 17; ++it) {
        __syncthreads();
#pragma unroll
        for (int i = 0; i < 4; i++) {
            *reinterpret_cast<bf16x8*>(&Ksh[(srK + i * 32) * 64 + kws]) = kreg[i];
            *reinterpret_cast<bf16x8*>(&Vsh[(srV + i * 16) * 128 + vws]) = vreg[i];
        }
        __syncthreads();

        if (it + 1 < 17) {
            const int nkv0 = (it + 1 < nL) ? (it + 1) * 128 : (it + 1 - nL) * 128;
#pragma unroll
            for (int i = 0; i < 4; i++) {
                kreg[i] = *reinterpret_cast<const bf16x8*>(KbS + (size_t)nkv0 * HD + i * 32 * HD);
                vreg[i] = *reinterpret_cast<const bf16x8*>(VbS + nkv0 + i * 16 * S_);
            }
        }

        if (it == nL) {
            float lq[4];
#pragma unroll
            for (int r = 0; r < 4; r++) lq[r] = __shfl(l, lc * 4 + r);
#pragma unroll
            for (int r = 0; r < 4; r++) {
                float inv = 1.f / lq[r];
                int qr = qLrow0 + lc * 4 + r;
#pragma unroll
                for (int dt = 0; dt < 4; dt++)
                    O[((size_t)(bb * S_ + qr)) * E_ + hh * HD + dt * 16 + lr] = f2bf(o[dt][r] * inv);
            }
            m = -INFINITY; l = 0.f;
#pragma unroll
            for (int dt = 0; dt < 4; dt++)
#pragma unroll
                for (int r = 0; r < 4; r++) o[dt][r] = 0.f;
            aq0 = aqH[0]; aq1 = aqH[1];
            qrow = qHrow0 + lr;
        }

        const int kv0 = (it < nL) ? it * 128 : (it - nL) * 128;
        const bool needMask = (it == nL - 1) || (it == 16);

        float p[8][4];
#pragma unroll
        for (int kt = 0; kt < 8; kt++) {
            const int row = kt * 16 + lr;
            const bf16x8 bk0 = *reinterpret_cast<const bf16x8*>(&Ksh[row * 64 + ((lc ^ r7) << 3)]);
            const bf16x8 bk1 = *reinterpret_cast<const bf16x8*>(&Ksh[row * 64 + (((4 + lc) ^ r7) << 3)]);
            f32x4 s = {};
            s = __builtin_amdgcn_mfma_f32_16x16x32_bf16(bk0, aq0, s, 0, 0, 0);
            s = __builtin_amdgcn_mfma_f32_16x16x32_bf16(bk1, aq1, s, 0, 0, 0);
#pragma unroll
            for (int r = 0; r < 4; r++) p[kt][r] = s[r];
        }
        if (needMask) {
#pragma unroll
            for (int kt = 0; kt < 8; kt++) {
                const int kbase = kv0 + kt * 16 + lc * 4;
#pragma unroll
                for (int r = 0; r < 4; r++)
                    if (kbase + r > qrow) p[kt][r] = -1e30f;
            }
        }

        float rm = -1e30f;
#pragma unroll
        for (int kt = 0; kt < 8; kt++)
#pragma unroll
            for (int r = 0; r < 4; r++) rm = fmaxf(rm, p[kt][r]);
        rm = fmaxf(rm, __shfl_xor(rm, 16));
        rm = fmaxf(rm, __shfl_xor(rm, 32));

        float mn = fmaxf(m, rm);
        float sc = __expf(m - mn);
        float rs = 0.f;
#pragma unroll
        for (int kt = 0; kt < 8; kt++)
#pragma unroll
            for (int r = 0; r < 4; r++) {
                float e = __expf(p[kt][r] - mn);
                p[kt][r] = e; rs += e;
            }
        rs += __shfl_xor(rs, 16);
        rs += __shfl_xor(rs, 32);
        l = l * sc + rs;
        m = mn;

        float scq[4];
#pragma unroll
        for (int r = 0; r < 4; r++) scq[r] = __shfl(sc, lc * 4 + r);
#pragma unroll
        for (int dt = 0; dt < 4; dt++)
#pragma unroll
            for (int r = 0; r < 4; r++) o[dt][r] *= scq[r];

#pragma unroll
        for (int kt = 0; kt < 8; kt++) {
            bf16x4 pv4;
            pv4[0] = (__bf16)p[kt][0]; pv4[1] = (__bf16)p[kt][1];
            pv4[2] = (__bf16)p[kt][2]; pv4[3] = (__bf16)p[kt][3];
            const int phys = (2 * kt + (lc >> 1)) ^ r7;
            *reinterpret_cast<bf16x4*>(&Pl[w][lr * 128 + phys * 8 + (lc & 1) * 4]) = pv4;
        }
        asm volatile("s_waitcnt lgkmcnt(0)" ::: "memory");
        __builtin_amdgcn_sched_barrier(0);

        bf16x8 ap[4];
#pragma unroll
        for (int kc = 0; kc < 4; kc++)
            ap[kc] = *reinterpret_cast<const bf16x8*>(&Pl[w][lr * 128 + (((kc * 4 + lc) ^ r7) << 3)]);

#pragma unroll
        for (int dt = 0; dt < 4; dt++) {
            const int row = dt * 16 + lr;
#pragma unroll
            for (int kc = 0; kc < 4; kc++) {
                const bf16x8 bv = *reinterpret_cast<const bf16x8*>(
                    &Vsh[row * 128 + (((kc * 4 + lc) ^ lr) << 3)]);
                o[dt] = __builtin_amdgcn_mfma_f32_16x16x32_bf16(ap[kc], bv, o[dt], 0, 0, 0);
            }
        }
    }

    {
        float lq[4];
#pragma unroll
        for (int r = 0; r < 4; r++) lq[r] = __shfl(l, lc * 4 + r);
#pragma unroll
        for (int r = 0; r < 4; r++) {
            float inv = 1.f / lq[r];
            int qr = qHrow0 + lc * 4 + r;
#pragma unroll
            for (int dt = 0; dt < 4; dt++)
                O[((size_t)(bb * S_ + qr)) * E_ + hh * HD + dt * 16 + lr] = f2bf(o[dt][r] * inv);
        }
    }
}

extern "C" void kernel_launch(void* const* d_in, const int* in_sizes, int n_in,
                              void* d_out, int out_size, void* d_ws, size_t ws_size,
                              hipStream_t stream) {
    const float* x      = (const float*)d_in[0];
    const float* w_attn = (const float*)d_in[1];
    const float* b_attn = (const float*)d_in[2];
    const float* w_proj = (const float*)d_in[3];
    const float* b_proj = (const float*)d_in[4];
    float* out = (float*)d_out;

    char* ws = (char*)d_ws;
    const size_t M = (size_t)B_ * S_;             // 8192
    unsigned short* xb  = (unsigned short*)(ws);                         // 8192*768
    unsigned short* waT = (unsigned short*)(ws + 12582912);              // 2304*768
    unsigned short* wpT = (unsigned short*)(ws + 16121856);              // 768*768
    unsigned short* Qb  = (unsigned short*)(ws + 17301504);              // BH*S*D
    unsigned short* Kb  = (unsigned short*)(ws + 29884416);
    unsigned short* Vt  = (unsigned short*)(ws + 42467328);
    unsigned short* AO  = (unsigned short*)(ws + 55050240);              // 8192*768

    int n4 = (int)(M * E_ / 4);
    cvt_kernel<<<(n4 + 255) / 256, 256, 0, stream>>>(x, xb, n4);
    transpose_cvt<<<dim3(3 * E_ / 32, E_ / 32), dim3(32, 32), 0, stream>>>(w_attn, waT, E_, 3 * E_);
    transpose_cvt<<<dim3(E_ / 32, E_ / 32), dim3(32, 32), 0, stream>>>(w_proj, wpT, E_, E_);

    gemm16<0><<<1152, 256, 0, stream>>>(
        xb, waT, b_attn, Qb, Kb, Vt, nullptr, (int)M, 3 * E_, E_);

    attn_kernel<<<768, 256, 0, stream>>>(Qb, Kb, Vt, AO);

    gemm16<1><<<384, 256, 0, stream>>>(
        AO, wpT, b_proj, nullptr, nullptr, nullptr, out, (int)M, E_, E_);
}